// Round 1
// baseline (1509.106 us; speedup 1.0000x reference)
//
#include <hip/hip_runtime.h>
#include <math.h>

// Problem constants
static constexpr int B_  = 2;
static constexpr int T_  = 512;
static constexpr int S_  = 2048;
static constexpr int H_  = 768;
static constexpr int L_  = 32;
static constexpr int NH_ = 12;
static constexpr int HD_ = 64;   // H/NH
static constexpr int IM_ = 3072; // 4*H

// ---------------------------------------------------------------------------
// Mask normalization: detect whether span_masks arrived as int32 or as packed
// bytes (jax bool). First 1024 ints all in {0,1} => int32 layout.
__global__ void k_mask(const int* __restrict__ raw, int* __restrict__ mout) {
    __shared__ int bad;
    if (threadIdx.x == 0) bad = 0;
    __syncthreads();
    int v = raw[threadIdx.x];           // 1024 threads, 1024 ints = 4096 bytes min
    if (v != 0 && v != 1) bad = 1;      // benign race, all writers store 1
    __syncthreads();
    int byte_layout = bad;
    const unsigned char* rb = (const unsigned char*)raw;
    for (int i = threadIdx.x; i < B_ * S_; i += 1024)
        mout[i] = byte_layout ? (int)rb[i] : raw[i];
}

// q[i] = sum_h dq[h] * Wq[i,h] + bq[i]   (Wq = in_proj_w rows [0,768))
__global__ void k_q(const float* __restrict__ dq, const float* __restrict__ w,
                    const float* __restrict__ b, float* __restrict__ q) {
    int i = blockIdx.x * 256 + threadIdx.x;
    if (i >= H_) return;
    const float* row = w + (size_t)i * H_;
    float acc = b[i];
    for (int h = 0; h < H_; ++h) acc += dq[h] * row[h];
    q[i] = acc;
}

// Wq_eff[n,hh] = sum_d q[n*64+d] * Wk[n*64+d, hh]  (Wk = in_proj_w rows [768,1536))
__global__ void k_wqeff(const float* __restrict__ q, const float* __restrict__ w,
                        float* __restrict__ wq) {
    int i = blockIdx.x * 256 + threadIdx.x;
    if (i >= NH_ * H_) return;
    int n = i / H_, hh = i % H_;
    float acc = 0.f;
    for (int d = 0; d < HD_; ++d)
        acc += q[n * HD_ + d] * w[(size_t)(H_ + n * HD_ + d) * H_ + hh];
    wq[i] = acc;
}

// x = token_reps + pe (pe broadcast over batch)
__global__ void k_addpe(const float* __restrict__ tr, const float* __restrict__ pe,
                        float* __restrict__ x) {
    int i = blockIdx.x * 256 + threadIdx.x;
    if (i >= B_ * T_ * H_) return;
    x[i] = tr[i] + pe[i % (T_ * H_)];
}

// stok[bt, n] = x[bt,:] . Wq_eff[n,:]
__global__ void k_stok(const float* __restrict__ x, const float* __restrict__ wq,
                       float* __restrict__ stok) {
    int i = blockIdx.x * 256 + threadIdx.x;
    if (i >= B_ * T_ * NH_) return;
    int bt = i / NH_, n = i % NH_;
    const float* xr = x + (size_t)bt * H_;
    const float* wr = wq + (size_t)n * H_;
    float acc = 0.f;
    for (int h = 0; h < H_; ++h) acc += xr[h] * wr[h];
    stok[i] = acc;
}

// ---------------------------------------------------------------------------
// Generic fp32 GEMM: C[M,N] = A[M,K] @ B[N,K]^T + bias[N], optional ReLU.
// BM=BN=64, BK=16, block 16x16, each thread 4x4 microtile.
template <bool RELU>
__global__ void gemm_nt(const float* __restrict__ A, const float* __restrict__ Bm,
                        const float* __restrict__ bias, float* __restrict__ C,
                        int M, int N, int K) {
    constexpr int BM = 64, BN = 64, BK = 16;
    __shared__ float As[BK][BM + 1];
    __shared__ float Bs[BK][BN + 1];
    int bm = blockIdx.y * BM, bn = blockIdx.x * BN;
    int tx = threadIdx.x, ty = threadIdx.y;   // 16 x 16
    int tid = ty * 16 + tx;
    float acc[4][4] = {};
    for (int k0 = 0; k0 < K; k0 += BK) {
        for (int i = tid; i < BM * BK; i += 256) {
            int m = i / BK, k = i % BK;
            As[k][m] = A[(size_t)(bm + m) * K + k0 + k];
        }
        for (int i = tid; i < BN * BK; i += 256) {
            int n = i / BK, k = i % BK;
            Bs[k][n] = Bm[(size_t)(bn + n) * K + k0 + k];
        }
        __syncthreads();
#pragma unroll
        for (int k = 0; k < BK; ++k) {
            float a[4], bb[4];
#pragma unroll
            for (int i = 0; i < 4; ++i) a[i] = As[k][ty * 4 + i];
#pragma unroll
            for (int j = 0; j < 4; ++j) bb[j] = Bs[k][tx * 4 + j];
#pragma unroll
            for (int i = 0; i < 4; ++i)
#pragma unroll
                for (int j = 0; j < 4; ++j) acc[i][j] += a[i] * bb[j];
        }
        __syncthreads();
    }
#pragma unroll
    for (int i = 0; i < 4; ++i) {
        int m = bm + ty * 4 + i;
#pragma unroll
        for (int j = 0; j < 4; ++j) {
            int n = bn + tx * 4 + j;
            float v = acc[i][j] + bias[n];
            if (RELU) v = fmaxf(v, 0.f);
            C[(size_t)m * N + n] = v;
        }
    }
}

// ---------------------------------------------------------------------------
// Per-span attention: softmax over <=32 precomputed scores, weighted sum of
// v_tok rows. One block per (b,s) row; 256 threads.
__global__ void k_attn(const float* __restrict__ stok, const float* __restrict__ vtok,
                       const int* __restrict__ span_ids, const int* __restrict__ masks,
                       float* __restrict__ ctx) {
    int r = blockIdx.x;                 // 0 .. B*S-1
    int b = r / S_;
    float* out = ctx + (size_t)r * H_;
    int tid = threadIdx.x;
    __shared__ float w[NH_][L_];
    __shared__ int idxs[L_];
    __shared__ int s_len;
    if (tid == 0) {
        int m = masks[r];
        int st = span_ids[2 * r], en = span_ids[2 * r + 1];
        int len = m ? (en - st) : 0;
        if (len < 0) len = 0;
        if (len > L_) len = L_;
        s_len = len;
    }
    __syncthreads();
    int len = s_len;
    if (len == 0) {                     // masked row: ctx=0, output zeroed later
        for (int h = tid; h < H_; h += 256) out[h] = 0.f;
        return;
    }
    if (tid < L_) {
        int p = span_ids[2 * r] + tid;
        p = p < 0 ? 0 : (p > T_ - 1 ? T_ - 1 : p);
        idxs[tid] = p;
    }
    __syncthreads();
    for (int i = tid; i < NH_ * L_; i += 256) {
        int n = i / L_, l = i % L_;
        float sc = -INFINITY;
        if (l < len) sc = stok[(size_t)(b * T_ + idxs[l]) * NH_ + n] * 0.125f;
        w[n][l] = sc;
    }
    __syncthreads();
    if (tid < NH_) {                    // tiny per-head softmax
        float mx = -INFINITY;
        for (int l = 0; l < len; ++l) mx = fmaxf(mx, w[tid][l]);
        float sum = 0.f;
        for (int l = 0; l < len; ++l) { float e = expf(w[tid][l] - mx); w[tid][l] = e; sum += e; }
        float inv = 1.f / sum;
        for (int l = 0; l < len; ++l) w[tid][l] *= inv;
        for (int l = len; l < L_; ++l) w[tid][l] = 0.f;
    }
    __syncthreads();
    for (int h = tid; h < H_; h += 256) {
        int n = h >> 6;
        float acc = 0.f;
        for (int l = 0; l < len; ++l)
            acc += w[n][l] * vtok[(size_t)(b * T_ + idxs[l]) * H_ + h];
        out[h] = acc;
    }
}

// ---------------------------------------------------------------------------
// LayerNorm over H=768: out = LN(inp + res)*[g,b], optionally * mask.
// res_broadcast: res is a single (H,) vector; else per-row.
__global__ void k_ln(const float* __restrict__ inp, const float* __restrict__ res,
                     const float* __restrict__ g, const float* __restrict__ bt,
                     float* __restrict__ outp, const int* __restrict__ masks,
                     int res_broadcast, int apply_mask) {
    int r = blockIdx.x;
    const float* irow = inp + (size_t)r * H_;
    const float* rrow = res_broadcast ? res : res + (size_t)r * H_;
    float* orow = outp + (size_t)r * H_;
    int tid = threadIdx.x;              // 256 threads, 3 elems each
    float v[3];
    float lsum = 0.f;
#pragma unroll
    for (int i = 0; i < 3; ++i) {
        int h = tid + 256 * i;
        v[i] = irow[h] + rrow[h];
        lsum += v[i];
    }
    __shared__ float sh[256];
    sh[tid] = lsum;
    __syncthreads();
    for (int st = 128; st > 0; st >>= 1) {
        if (tid < st) sh[tid] += sh[tid + st];
        __syncthreads();
    }
    float mean = sh[0] * (1.f / H_);
    __syncthreads();
    float lvar = 0.f;
#pragma unroll
    for (int i = 0; i < 3; ++i) { float d = v[i] - mean; lvar += d * d; }
    sh[tid] = lvar;
    __syncthreads();
    for (int st = 128; st > 0; st >>= 1) {
        if (tid < st) sh[tid] += sh[tid + st];
        __syncthreads();
    }
    float var = sh[0] * (1.f / H_);
    float scale = rsqrtf(var + 1e-5f);
    float mfac = apply_mask ? (masks[r] ? 1.f : 0.f) : 1.f;
#pragma unroll
    for (int i = 0; i < 3; ++i) {
        int h = tid + 256 * i;
        orow[h] = ((v[i] - mean) * scale * g[h] + bt[h]) * mfac;
    }
}

// ---------------------------------------------------------------------------
extern "C" void kernel_launch(void* const* d_in, const int* in_sizes, int n_in,
                              void* d_out, int out_size, void* d_ws, size_t ws_size,
                              hipStream_t stream) {
    const float* token_reps = (const float*)d_in[0];
    const int*   span_ids   = (const int*)d_in[1];
    const int*   masks_raw  = (const int*)d_in[2];
    // d_in[3] = pooling (unused, always 0 in this dataset)
    const float* pe   = (const float*)d_in[4];
    const float* dq   = (const float*)d_in[5];
    const float* in_w = (const float*)d_in[6];
    const float* in_b = (const float*)d_in[7];
    const float* ow   = (const float*)d_in[8];
    const float* ob   = (const float*)d_in[9];
    const float* g    = (const float*)d_in[10];
    const float* bt   = (const float*)d_in[11];
    const float* w1   = (const float*)d_in[12];
    const float* b1   = (const float*)d_in[13];
    const float* w2   = (const float*)d_in[14];
    const float* b2   = (const float*)d_in[15];

    // Workspace layout (floats)
    float* ws    = (float*)d_ws;
    float* x     = ws;                       // B*T*H     = 786432
    float* vtok  = x + B_ * T_ * H_;         // 786432
    float* stok  = vtok + B_ * T_ * H_;      // B*T*NH    = 12288
    float* qv    = stok + B_ * T_ * NH_;     // 768
    float* wqeff = qv + H_;                  // NH*H      = 9216
    float* ctx   = wqeff + NH_ * H_;         // B*S*H     = 3145728
    float* x1b   = ctx + (size_t)B_ * S_ * H_;   // 3145728
    float* f1    = x1b + (size_t)B_ * S_ * H_;   // B*S*IM  = 12582912
    int*   maskn = (int*)(f1 + (size_t)B_ * S_ * IM_); // B*S ints
    float* f2    = ctx;                      // reuse ctx after A1 is consumed

    const int BS = B_ * S_;

    // 0. normalize masks
    k_mask<<<1, 1024, 0, stream>>>(masks_raw, maskn);
    // 1. q vector, effective per-head score weights
    k_q<<<(H_ + 255) / 256, 256, 0, stream>>>(dq, in_w, in_b, qv);
    k_wqeff<<<(NH_ * H_ + 255) / 256, 256, 0, stream>>>(qv, in_w, wqeff);
    // 2. x = token_reps + pe
    k_addpe<<<(B_ * T_ * H_ + 255) / 256, 256, 0, stream>>>(token_reps, pe, x);
    // 3. per-token score table
    k_stok<<<(B_ * T_ * NH_ + 255) / 256, 256, 0, stream>>>(x, wqeff, stok);
    // 4. v_tok = x @ Wv^T + bv   (Wv = in_proj_w rows [1536,2304))
    {
        dim3 grid(H_ / 64, (B_ * T_) / 64), blk(16, 16);
        gemm_nt<false><<<grid, blk, 0, stream>>>(x, in_w + (size_t)2 * H_ * H_,
                                                 in_b + 2 * H_, vtok,
                                                 B_ * T_, H_, H_);
    }
    // 5. attention pooling -> ctx
    k_attn<<<BS, 256, 0, stream>>>(stok, vtok, span_ids, maskn, ctx);
    // 6. A1 = ctx @ out_proj_w^T + ob  -> x1b
    {
        dim3 grid(H_ / 64, BS / 64), blk(16, 16);
        gemm_nt<false><<<grid, blk, 0, stream>>>(ctx, ow, ob, x1b, BS, H_, H_);
    }
    // 7. x1 = LN(A1 + dummy_query)  (in place)
    k_ln<<<BS, 256, 0, stream>>>(x1b, dq, g, bt, x1b, nullptr, 1, 0);
    // 8. F1 = relu(x1 @ w1^T + b1)
    {
        dim3 grid(IM_ / 64, BS / 64), blk(16, 16);
        gemm_nt<true><<<grid, blk, 0, stream>>>(x1b, w1, b1, f1, BS, IM_, H_);
    }
    // 9. F2 = F1 @ w2^T + b2  -> f2 (reuses ctx)
    {
        dim3 grid(H_ / 64, BS / 64), blk(16, 16);
        gemm_nt<false><<<grid, blk, 0, stream>>>(f1, w2, b2, f2, BS, H_, IM_);
    }
    // 10. out = LN(F2 + x1) * mask
    k_ln<<<BS, 256, 0, stream>>>(f2, x1b, g, bt, (float*)d_out, maskn, 0, 1);
}

// Round 2
// 334.308 us; speedup vs baseline: 4.5141x; 4.5141x over previous
//
#include <hip/hip_runtime.h>
#include <math.h>

// Problem constants
static constexpr int B_  = 2;
static constexpr int T_  = 512;
static constexpr int S_  = 2048;
static constexpr int H_  = 768;
static constexpr int L_  = 32;
static constexpr int NH_ = 12;
static constexpr int HD_ = 64;   // H/NH
static constexpr int IM_ = 3072; // 4*H

typedef __bf16 bf16x8 __attribute__((ext_vector_type(8)));
typedef float  f32x4  __attribute__((ext_vector_type(4)));

__device__ __forceinline__ float bf2f(unsigned short u) {
    return __uint_as_float(((unsigned)u) << 16);
}
__device__ __forceinline__ unsigned short f2bf(float f) {
    unsigned u = __float_as_uint(f);
    u += 0x7fffu + ((u >> 16) & 1u);   // RNE
    return (unsigned short)(u >> 16);
}
__device__ __forceinline__ void gl_lds16(const void* g, void* l) {
    __builtin_amdgcn_global_load_lds((const __attribute__((address_space(1))) void*)g,
                                     (__attribute__((address_space(3))) void*)l, 16, 0, 0);
}

// ---------------------------------------------------------------------------
// Mask normalization (int32 vs packed-byte autodetect, same as R1 which passed)
__global__ void k_mask(const int* __restrict__ raw, int* __restrict__ mout) {
    __shared__ int bad;
    if (threadIdx.x == 0) bad = 0;
    __syncthreads();
    int v = raw[threadIdx.x];
    if (v != 0 && v != 1) bad = 1;
    __syncthreads();
    int byte_layout = bad;
    const unsigned char* rb = (const unsigned char*)raw;
    for (int i = threadIdx.x; i < B_ * S_; i += 1024)
        mout[i] = byte_layout ? (int)rb[i] : raw[i];
}

// q[i] = dq . Wq[i,:] + bq[i]
__global__ void k_q(const float* __restrict__ dq, const float* __restrict__ w,
                    const float* __restrict__ b, float* __restrict__ q) {
    int i = blockIdx.x * 256 + threadIdx.x;
    if (i >= H_) return;
    const float* row = w + (size_t)i * H_;
    float acc = b[i];
    for (int h = 0; h < H_; ++h) acc += dq[h] * row[h];
    q[i] = acc;
}

// Wq_eff[n,hh] = sum_d q[n*64+d] * Wk[n*64+d, hh]
__global__ void k_wqeff(const float* __restrict__ q, const float* __restrict__ w,
                        float* __restrict__ wq) {
    int i = blockIdx.x * 256 + threadIdx.x;
    if (i >= NH_ * H_) return;
    int n = i / H_, hh = i % H_;
    float acc = 0.f;
    for (int d = 0; d < HD_; ++d)
        acc += q[n * HD_ + d] * w[(size_t)(H_ + n * HD_ + d) * H_ + hh];
    wq[i] = acc;
}

// fp32 -> bf16 cast, 4 elems/thread
__global__ void k_cast(const float* __restrict__ src, unsigned short* __restrict__ dst, int n) {
    int i = (blockIdx.x * 256 + threadIdx.x) * 4;
    if (i >= n) return;
    float4 f = *(const float4*)(src + i);
    uint2 o;
    o.x = (unsigned)f2bf(f.x) | ((unsigned)f2bf(f.y) << 16);
    o.y = (unsigned)f2bf(f.z) | ((unsigned)f2bf(f.w) << 16);
    *(uint2*)(dst + i) = o;
}

// x_bf = bf16(token_reps + pe)
__global__ void k_addpe(const float* __restrict__ tr, const float* __restrict__ pe,
                        unsigned short* __restrict__ x) {
    int i = (blockIdx.x * 256 + threadIdx.x) * 4;
    if (i >= B_ * T_ * H_) return;
    float4 a = *(const float4*)(tr + i);
    float4 p = *(const float4*)(pe + (i % (T_ * H_)));
    uint2 o;
    o.x = (unsigned)f2bf(a.x + p.x) | ((unsigned)f2bf(a.y + p.y) << 16);
    o.y = (unsigned)f2bf(a.z + p.z) | ((unsigned)f2bf(a.w + p.w) << 16);
    *(uint2*)(x + i) = o;
}

// stok[bt,n] = x_bf[bt,:] . wqeff[n,:]  — one block per bt, wave w does heads 3w..3w+2
__global__ void k_stok(const unsigned short* __restrict__ x, const float* __restrict__ wq,
                       float* __restrict__ stok) {
    int bt = blockIdx.x;
    int lane = threadIdx.x & 63, w = threadIdx.x >> 6;
    const unsigned short* xr = x + (size_t)bt * H_;
    float xv[12];
#pragma unroll
    for (int k = 0; k < 12; ++k) xv[k] = bf2f(xr[lane + 64 * k]);
#pragma unroll
    for (int hh = 0; hh < 3; ++hh) {
        int n = w * 3 + hh;
        const float* wr = wq + (size_t)n * H_;
        float acc = 0.f;
#pragma unroll
        for (int k = 0; k < 12; ++k) acc += xv[k] * wr[lane + 64 * k];
        for (int m = 32; m; m >>= 1) acc += __shfl_xor(acc, m, 64);
        if (lane == 0) stok[bt * NH_ + n] = acc;
    }
}

// ---------------------------------------------------------------------------
// bf16 MFMA GEMM (m97 structure): C[M,N] = A[M,K] @ W[N,K]^T + bias, opt ReLU.
// 128x128 tile, BK=32, 256 thr = 4 waves, each wave 64x64 = 4x4 MFMA 16x16x32.
template <bool RELU, bool OBF>
__global__ __launch_bounds__(256)
void gemm_bt(const unsigned short* __restrict__ A, const unsigned short* __restrict__ W,
             const float* __restrict__ bias, void* __restrict__ Cout,
             int M, int N, int K) {
    __shared__ unsigned short As[128 * 32];
    __shared__ unsigned short Bs[128 * 32];
    const int bm = blockIdx.y * 128, bn = blockIdx.x * 128;
    const int tid = threadIdx.x, lane = tid & 63, wid = tid >> 6;
    const int wm = (wid >> 1) * 64, wn = (wid & 1) * 64;
    // staging: 8 chunks of 1KB per tile; wave w owns chunks {w, w+4}
    const int r4 = lane >> 2, kg = (lane & 3) * 8;
    const unsigned short* agp0 = A + (size_t)(bm + wid * 16 + r4) * K + kg;
    const unsigned short* agp1 = A + (size_t)(bm + (wid + 4) * 16 + r4) * K + kg;
    const unsigned short* bgp0 = W + (size_t)(bn + wid * 16 + r4) * K + kg;
    const unsigned short* bgp1 = W + (size_t)(bn + (wid + 4) * 16 + r4) * K + kg;
    unsigned short* lA0 = As + wid * 512;        // wave-uniform LDS bases
    unsigned short* lA1 = As + (wid + 4) * 512;
    unsigned short* lB0 = Bs + wid * 512;
    unsigned short* lB1 = Bs + (wid + 4) * 512;

    f32x4 acc[4][4];
#pragma unroll
    for (int i = 0; i < 4; ++i)
#pragma unroll
        for (int j = 0; j < 4; ++j) acc[i][j] = f32x4{0.f, 0.f, 0.f, 0.f};

    const int mrow = lane & 15, kq = (lane >> 4) * 8;

    for (int k0 = 0; k0 < K; k0 += 32) {
        __syncthreads();
        gl_lds16(agp0 + k0, lA0);
        gl_lds16(agp1 + k0, lA1);
        gl_lds16(bgp0 + k0, lB0);
        gl_lds16(bgp1 + k0, lB1);
        __syncthreads();
        bf16x8 af[4], bfr[4];
#pragma unroll
        for (int i = 0; i < 4; ++i)
            af[i] = *(const bf16x8*)(As + (wm + i * 16 + mrow) * 32 + kq);
#pragma unroll
        for (int j = 0; j < 4; ++j)
            bfr[j] = *(const bf16x8*)(Bs + (wn + j * 16 + mrow) * 32 + kq);
#pragma unroll
        for (int i = 0; i < 4; ++i)
#pragma unroll
            for (int j = 0; j < 4; ++j)
                acc[i][j] = __builtin_amdgcn_mfma_f32_16x16x32_bf16(af[i], bfr[j], acc[i][j], 0, 0, 0);
    }

    // epilogue: C/D layout col=lane&15, row=(lane>>4)*4+reg (verified m89/m91)
    const int lr = (lane >> 4) * 4, lc = lane & 15;
#pragma unroll
    for (int j = 0; j < 4; ++j) {
        int col = bn + wn + j * 16 + lc;
        float bv = bias[col];
#pragma unroll
        for (int i = 0; i < 4; ++i) {
            int row0 = bm + wm + i * 16 + lr;
#pragma unroll
            for (int r = 0; r < 4; ++r) {
                float v = acc[i][j][r] + bv;
                if (RELU) v = fmaxf(v, 0.f);
                if (OBF)
                    ((unsigned short*)Cout)[(size_t)(row0 + r) * N + col] = f2bf(v);
                else
                    ((float*)Cout)[(size_t)(row0 + r) * N + col] = v;
            }
        }
    }
}

// ---------------------------------------------------------------------------
// Per-span attention: softmax over <=32 precomputed scores, weighted sum of
// bf16 V rows. One block per (b,s); 256 threads (192 active in V-accum).
__global__ void k_attn(const float* __restrict__ stok, const unsigned short* __restrict__ vtok,
                       const int* __restrict__ span_ids, const int* __restrict__ masks,
                       unsigned short* __restrict__ ctx) {
    int r = blockIdx.x, b = r / S_;
    unsigned short* out = ctx + (size_t)r * H_;
    int tid = threadIdx.x;
    __shared__ float w[NH_][L_];
    __shared__ int idxs[L_];
    __shared__ int s_len;
    if (tid == 0) {
        int m = masks[r];
        int st = span_ids[2 * r], en = span_ids[2 * r + 1];
        int len = m ? (en - st) : 0;
        len = len < 0 ? 0 : (len > L_ ? L_ : len);
        s_len = len;
    }
    __syncthreads();
    int len = s_len;
    if (len == 0) {
        for (int h2 = tid; h2 < H_ / 2; h2 += 256) ((unsigned*)out)[h2] = 0u;
        return;
    }
    if (tid < L_) {
        int p = span_ids[2 * r] + tid;
        idxs[tid] = p < 0 ? 0 : (p > T_ - 1 ? T_ - 1 : p);
    }
    __syncthreads();
    for (int i = tid; i < NH_ * L_; i += 256) {
        int n = i / L_, l = i % L_;
        w[n][l] = (l < len) ? stok[(size_t)(b * T_ + idxs[l]) * NH_ + n] * 0.125f : -INFINITY;
    }
    __syncthreads();
    if (tid < NH_) {
        float mx = -INFINITY;
        for (int l = 0; l < len; ++l) mx = fmaxf(mx, w[tid][l]);
        float sum = 0.f;
        for (int l = 0; l < len; ++l) { float e = __expf(w[tid][l] - mx); w[tid][l] = e; sum += e; }
        float inv = 1.f / sum;
        for (int l = 0; l < len; ++l) w[tid][l] *= inv;
    }
    __syncthreads();
    if (tid < 192) {
        int h0 = tid * 4, n = h0 >> 6;
        float a0 = 0.f, a1 = 0.f, a2 = 0.f, a3 = 0.f;
        for (int l = 0; l < len; ++l) {
            float wl = w[n][l];
            const unsigned short* vr = vtok + (size_t)(b * T_ + idxs[l]) * H_ + h0;
            uint2 u = *(const uint2*)vr;
            a0 += wl * bf2f((unsigned short)(u.x & 0xffff));
            a1 += wl * bf2f((unsigned short)(u.x >> 16));
            a2 += wl * bf2f((unsigned short)(u.y & 0xffff));
            a3 += wl * bf2f((unsigned short)(u.y >> 16));
        }
        uint2 o;
        o.x = (unsigned)f2bf(a0) | ((unsigned)f2bf(a1) << 16);
        o.y = (unsigned)f2bf(a2) | ((unsigned)f2bf(a3) << 16);
        *(uint2*)(out + h0) = o;
    }
}

// ---------------------------------------------------------------------------
// LayerNorm: out = LN(inp + res)*g + b, optional mask-zero, optional bf16 copy.
__global__ void k_ln(const float* __restrict__ inp, const float* __restrict__ res,
                     const float* __restrict__ g, const float* __restrict__ bt,
                     float* __restrict__ outp, unsigned short* __restrict__ outbf,
                     const int* __restrict__ masks, int res_broadcast, int apply_mask) {
    int r = blockIdx.x;
    const float* irow = inp + (size_t)r * H_;
    const float* rrow = res_broadcast ? res : res + (size_t)r * H_;
    float* orow = outp + (size_t)r * H_;
    int tid = threadIdx.x;
    float v[3];
    float lsum = 0.f;
#pragma unroll
    for (int i = 0; i < 3; ++i) {
        int h = tid + 256 * i;
        v[i] = irow[h] + rrow[h];
        lsum += v[i];
    }
    __shared__ float sh[256];
    sh[tid] = lsum;
    __syncthreads();
    for (int st = 128; st > 0; st >>= 1) {
        if (tid < st) sh[tid] += sh[tid + st];
        __syncthreads();
    }
    float mean = sh[0] * (1.f / H_);
    __syncthreads();
    float lvar = 0.f;
#pragma unroll
    for (int i = 0; i < 3; ++i) { float d = v[i] - mean; lvar += d * d; }
    sh[tid] = lvar;
    __syncthreads();
    for (int st = 128; st > 0; st >>= 1) {
        if (tid < st) sh[tid] += sh[tid + st];
        __syncthreads();
    }
    float var = sh[0] * (1.f / H_);
    float scale = rsqrtf(var + 1e-5f);
    float mfac = apply_mask ? (masks[r] ? 1.f : 0.f) : 1.f;
#pragma unroll
    for (int i = 0; i < 3; ++i) {
        int h = tid + 256 * i;
        float o = ((v[i] - mean) * scale * g[h] + bt[h]) * mfac;
        orow[h] = o;
        if (outbf) outbf[(size_t)r * H_ + h] = f2bf(o);
    }
}

// ---------------------------------------------------------------------------
extern "C" void kernel_launch(void* const* d_in, const int* in_sizes, int n_in,
                              void* d_out, int out_size, void* d_ws, size_t ws_size,
                              hipStream_t stream) {
    const float* token_reps = (const float*)d_in[0];
    const int*   span_ids   = (const int*)d_in[1];
    const int*   masks_raw  = (const int*)d_in[2];
    const float* pe   = (const float*)d_in[4];
    const float* dq   = (const float*)d_in[5];
    const float* in_w = (const float*)d_in[6];
    const float* in_b = (const float*)d_in[7];
    const float* ow   = (const float*)d_in[8];
    const float* ob   = (const float*)d_in[9];
    const float* g    = (const float*)d_in[10];
    const float* bt   = (const float*)d_in[11];
    const float* w1   = (const float*)d_in[12];
    const float* b1   = (const float*)d_in[13];
    const float* w2   = (const float*)d_in[14];
    const float* b2   = (const float*)d_in[15];

    const int BS = B_ * S_;        // 4096
    const int BT = B_ * T_;        // 1024

    // Workspace layout
    float* fws   = (float*)d_ws;
    float* stok  = fws;                         // 12288
    float* qv    = stok + BT * NH_;             // 768
    float* wqeff = qv + H_;                     // 9216
    float* A1    = wqeff + NH_ * H_;            // 3145728 (reused as f2)
    float* x1f   = A1 + (size_t)BS * H_;        // 3145728
    unsigned short* us   = (unsigned short*)(x1f + (size_t)BS * H_);
    unsigned short* xbf  = us;                       // 786432
    unsigned short* vtok = xbf + (size_t)BT * H_;    // 786432
    unsigned short* ctx  = vtok + (size_t)BT * H_;   // 3145728
    unsigned short* x1bf = ctx + (size_t)BS * H_;    // 3145728
    unsigned short* f1   = x1bf + (size_t)BS * H_;   // 12582912
    unsigned short* wvb  = f1 + (size_t)BS * IM_;    // 589824
    unsigned short* owb  = wvb + H_ * H_;            // 589824
    unsigned short* w1b  = owb + H_ * H_;            // 2359296
    unsigned short* w2b  = w1b + IM_ * H_;           // 2359296
    int* maskn = (int*)(w2b + H_ * IM_);             // 4096
    float* f2 = A1;

    // 0. small prep
    k_mask<<<1, 1024, 0, stream>>>(masks_raw, maskn);
    k_q<<<(H_ + 255) / 256, 256, 0, stream>>>(dq, in_w, in_b, qv);
    k_wqeff<<<(NH_ * H_ + 255) / 256, 256, 0, stream>>>(qv, in_w, wqeff);
    // 1. weight casts to bf16
    k_cast<<<(H_ * H_ / 4 + 255) / 256, 256, 0, stream>>>(in_w + (size_t)2 * H_ * H_, wvb, H_ * H_);
    k_cast<<<(H_ * H_ / 4 + 255) / 256, 256, 0, stream>>>(ow, owb, H_ * H_);
    k_cast<<<(IM_ * H_ / 4 + 255) / 256, 256, 0, stream>>>(w1, w1b, IM_ * H_);
    k_cast<<<(H_ * IM_ / 4 + 255) / 256, 256, 0, stream>>>(w2, w2b, H_ * IM_);
    // 2. x = bf16(token_reps + pe)
    k_addpe<<<(BT * H_ / 4 + 255) / 256, 256, 0, stream>>>(token_reps, pe, xbf);
    // 3. per-token per-head scores
    k_stok<<<BT, 256, 0, stream>>>(xbf, wqeff, stok);
    // 4. vtok = bf16(x @ Wv^T + bv)
    {
        dim3 grid(H_ / 128, BT / 128);
        gemm_bt<false, true><<<grid, 256, 0, stream>>>(xbf, wvb, in_b + 2 * H_, vtok, BT, H_, H_);
    }
    // 5. attention pooling -> ctx (bf16)
    k_attn<<<BS, 256, 0, stream>>>(stok, vtok, span_ids, maskn, ctx);
    // 6. A1 = ctx @ ow^T + ob (fp32)
    {
        dim3 grid(H_ / 128, BS / 128);
        gemm_bt<false, false><<<grid, 256, 0, stream>>>(ctx, owb, ob, A1, BS, H_, H_);
    }
    // 7. x1 = LN(A1 + dq) -> fp32 + bf16
    k_ln<<<BS, 256, 0, stream>>>(A1, dq, g, bt, x1f, x1bf, nullptr, 1, 0);
    // 8. f1 = bf16(relu(x1 @ w1^T + b1))
    {
        dim3 grid(IM_ / 128, BS / 128);
        gemm_bt<true, true><<<grid, 256, 0, stream>>>(x1bf, w1b, b1, f1, BS, IM_, H_);
    }
    // 9. f2 = f1 @ w2^T + b2 (fp32)
    {
        dim3 grid(H_ / 128, BS / 128);
        gemm_bt<false, false><<<grid, 256, 0, stream>>>(f1, w2b, b2, f2, BS, H_, IM_);
    }
    // 10. out = LN(f2 + x1) * mask
    k_ln<<<BS, 256, 0, stream>>>(f2, x1f, g, bt, (float*)d_out, nullptr, maskn, 0, 1);
}

// Round 3
// 308.885 us; speedup vs baseline: 4.8857x; 1.0823x over previous
//
#include <hip/hip_runtime.h>
#include <math.h>

// Problem constants
static constexpr int B_  = 2;
static constexpr int T_  = 512;
static constexpr int S_  = 2048;
static constexpr int H_  = 768;
static constexpr int L_  = 32;
static constexpr int NH_ = 12;
static constexpr int HD_ = 64;   // H/NH
static constexpr int IM_ = 3072; // 4*H

typedef __bf16 bf16x8 __attribute__((ext_vector_type(8)));
typedef float  f32x4  __attribute__((ext_vector_type(4)));

__device__ __forceinline__ float bf2f(unsigned short u) {
    return __uint_as_float(((unsigned)u) << 16);
}
__device__ __forceinline__ unsigned short f2bf(float f) {
    unsigned u = __float_as_uint(f);
    u += 0x7fffu + ((u >> 16) & 1u);   // RNE
    return (unsigned short)(u >> 16);
}
__device__ __forceinline__ void gl_lds16(const void* g, void* l) {
    __builtin_amdgcn_global_load_lds((const __attribute__((address_space(1))) void*)g,
                                     (__attribute__((address_space(3))) void*)l, 16, 0, 0);
}

// ---------------------------------------------------------------------------
// Mask normalization (int32 vs packed-byte autodetect)
__global__ void k_mask(const int* __restrict__ raw, int* __restrict__ mout) {
    __shared__ int bad;
    if (threadIdx.x == 0) bad = 0;
    __syncthreads();
    int v = raw[threadIdx.x];
    if (v != 0 && v != 1) bad = 1;
    __syncthreads();
    int byte_layout = bad;
    const unsigned char* rb = (const unsigned char*)raw;
    for (int i = threadIdx.x; i < B_ * S_; i += 1024)
        mout[i] = byte_layout ? (int)rb[i] : raw[i];
}

// q[i] = dq . Wq[i,:] + bq[i]
__global__ void k_q(const float* __restrict__ dq, const float* __restrict__ w,
                    const float* __restrict__ b, float* __restrict__ q) {
    int i = blockIdx.x * 256 + threadIdx.x;
    if (i >= H_) return;
    const float* row = w + (size_t)i * H_;
    float acc = b[i];
    for (int h = 0; h < H_; ++h) acc += dq[h] * row[h];
    q[i] = acc;
}

// Wq_eff[n,hh] = sum_d q[n*64+d] * Wk[n*64+d, hh]
__global__ void k_wqeff(const float* __restrict__ q, const float* __restrict__ w,
                        float* __restrict__ wq) {
    int i = blockIdx.x * 256 + threadIdx.x;
    if (i >= NH_ * H_) return;
    int n = i / H_, hh = i % H_;
    float acc = 0.f;
    for (int d = 0; d < HD_; ++d)
        acc += q[n * HD_ + d] * w[(size_t)(H_ + n * HD_ + d) * H_ + hh];
    wq[i] = acc;
}

// Fused weight cast: all four weight matrices fp32->bf16, 8 elems/thread.
__global__ void k_castw(const float* __restrict__ s0, const float* __restrict__ s1,
                        const float* __restrict__ s2, const float* __restrict__ s3,
                        unsigned short* __restrict__ d0, unsigned short* __restrict__ d1,
                        unsigned short* __restrict__ d2, unsigned short* __restrict__ d3) {
    const long n0 = (long)H_ * H_, n2 = (long)IM_ * H_;
    long gid = (long)(blockIdx.x * 256 + threadIdx.x) * 8;
    const float* s; unsigned short* d; long off;
    if (gid < n0)                { s = s0; d = d0; off = gid; }
    else if (gid < 2 * n0)       { s = s1; d = d1; off = gid - n0; }
    else if (gid < 2 * n0 + n2)  { s = s2; d = d2; off = gid - 2 * n0; }
    else                         { s = s3; d = d3; off = gid - 2 * n0 - n2; }
    float4 f0 = *(const float4*)(s + off);
    float4 f1 = *(const float4*)(s + off + 4);
    uint4 o;
    o.x = (unsigned)f2bf(f0.x) | ((unsigned)f2bf(f0.y) << 16);
    o.y = (unsigned)f2bf(f0.z) | ((unsigned)f2bf(f0.w) << 16);
    o.z = (unsigned)f2bf(f1.x) | ((unsigned)f2bf(f1.y) << 16);
    o.w = (unsigned)f2bf(f1.z) | ((unsigned)f2bf(f1.w) << 16);
    *(uint4*)(d + off) = o;
}

// x_bf = bf16(token_reps + pe), 8 elems/thread
__global__ void k_addpe(const float* __restrict__ tr, const float* __restrict__ pe,
                        unsigned short* __restrict__ x) {
    int i = (blockIdx.x * 256 + threadIdx.x) * 8;
    if (i >= B_ * T_ * H_) return;
    float4 a0 = *(const float4*)(tr + i);
    float4 a1 = *(const float4*)(tr + i + 4);
    const float* pp = pe + (i % (T_ * H_));
    float4 p0 = *(const float4*)pp;
    float4 p1 = *(const float4*)(pp + 4);
    uint4 o;
    o.x = (unsigned)f2bf(a0.x + p0.x) | ((unsigned)f2bf(a0.y + p0.y) << 16);
    o.y = (unsigned)f2bf(a0.z + p0.z) | ((unsigned)f2bf(a0.w + p0.w) << 16);
    o.z = (unsigned)f2bf(a1.x + p1.x) | ((unsigned)f2bf(a1.y + p1.y) << 16);
    o.w = (unsigned)f2bf(a1.z + p1.z) | ((unsigned)f2bf(a1.w + p1.w) << 16);
    *(uint4*)(x + i) = o;
}

// stok[bt,n] = x_bf[bt,:] . wqeff[n,:]
__global__ void k_stok(const unsigned short* __restrict__ x, const float* __restrict__ wq,
                       float* __restrict__ stok) {
    int bt = blockIdx.x;
    int lane = threadIdx.x & 63, w = threadIdx.x >> 6;
    const unsigned short* xr = x + (size_t)bt * H_;
    float xv[12];
#pragma unroll
    for (int k = 0; k < 12; ++k) xv[k] = bf2f(xr[lane + 64 * k]);
#pragma unroll
    for (int hh = 0; hh < 3; ++hh) {
        int n = w * 3 + hh;
        const float* wr = wq + (size_t)n * H_;
        float acc = 0.f;
#pragma unroll
        for (int k = 0; k < 12; ++k) acc += xv[k] * wr[lane + 64 * k];
        for (int m = 32; m; m >>= 1) acc += __shfl_xor(acc, m, 64);
        if (lane == 0) stok[bt * NH_ + n] = acc;
    }
}

// ---------------------------------------------------------------------------
// bf16 MFMA GEMM, double-buffered: C[M,N] = A[M,K] @ W[N,K]^T + bias, opt ReLU.
// 128x128 tile, BK=32, 512 thr = 8 waves, each wave 32x64 = 2x4 MFMA 16x16x32.
// One barrier per K-iter; tile k+1 prefetched (global_load_lds) into the
// alternate LDS buffer while tile k computes.
template <bool RELU, bool OBF>
__global__ __launch_bounds__(512)
void gemm_bt(const unsigned short* __restrict__ A, const unsigned short* __restrict__ W,
             const float* __restrict__ bias, void* __restrict__ Cout,
             int M, int N, int K) {
    __shared__ unsigned short As[2 * 128 * 32];
    __shared__ unsigned short Bs[2 * 128 * 32];
    const int bm = blockIdx.y * 128, bn = blockIdx.x * 128;
    const int tid = threadIdx.x, lane = tid & 63, wid = tid >> 6;   // 0..7
    const int wm = (wid >> 1) * 32, wn = (wid & 1) * 64;
    // staging: wave w loads rows [16w,16w+16) of A-tile and of B-tile (1KB each)
    const int r4 = lane >> 2, kg = (lane & 3) * 8;
    const unsigned short* agp = A + (size_t)(bm + wid * 16 + r4) * K + kg;
    const unsigned short* bgp = W + (size_t)(bn + wid * 16 + r4) * K + kg;

    f32x4 acc[2][4];
#pragma unroll
    for (int i = 0; i < 2; ++i)
#pragma unroll
        for (int j = 0; j < 4; ++j) acc[i][j] = f32x4{0.f, 0.f, 0.f, 0.f};

    const int mrow = lane & 15, kq = (lane >> 4) * 8;
    const int NIT = K >> 5;
    int cur = 0;
    // prologue: prefetch tile 0 into buffer 0
    gl_lds16(agp, As + wid * 512);
    gl_lds16(bgp, Bs + wid * 512);
    for (int it = 0; it < NIT; ++it) {
        __syncthreads();                       // buf[cur] ready; prev reads done
        if (it + 1 < NIT) {                    // prefetch next tile into buf[cur^1]
            int k0 = (it + 1) << 5;
            gl_lds16(agp + k0, As + (cur ^ 1) * 4096 + wid * 512);
            gl_lds16(bgp + k0, Bs + (cur ^ 1) * 4096 + wid * 512);
        }
        const unsigned short* cA = As + cur * 4096;
        const unsigned short* cB = Bs + cur * 4096;
        bf16x8 af[2], bfr[4];
#pragma unroll
        for (int i = 0; i < 2; ++i)
            af[i] = *(const bf16x8*)(cA + (wm + i * 16 + mrow) * 32 + kq);
#pragma unroll
        for (int j = 0; j < 4; ++j)
            bfr[j] = *(const bf16x8*)(cB + (wn + j * 16 + mrow) * 32 + kq);
#pragma unroll
        for (int i = 0; i < 2; ++i)
#pragma unroll
            for (int j = 0; j < 4; ++j)
                acc[i][j] = __builtin_amdgcn_mfma_f32_16x16x32_bf16(af[i], bfr[j], acc[i][j], 0, 0, 0);
        cur ^= 1;
    }

    // epilogue: C/D layout col=lane&15, row=(lane>>4)*4+reg (verified m89/m91)
    const int lr = (lane >> 4) * 4, lc = lane & 15;
#pragma unroll
    for (int j = 0; j < 4; ++j) {
        int col = bn + wn + j * 16 + lc;
        float bv = bias[col];
#pragma unroll
        for (int i = 0; i < 2; ++i) {
            int row0 = bm + wm + i * 16 + lr;
#pragma unroll
            for (int r = 0; r < 4; ++r) {
                float v = acc[i][j][r] + bv;
                if (RELU) v = fmaxf(v, 0.f);
                if (OBF)
                    ((unsigned short*)Cout)[(size_t)(row0 + r) * N + col] = f2bf(v);
                else
                    ((float*)Cout)[(size_t)(row0 + r) * N + col] = v;
            }
        }
    }
}

// ---------------------------------------------------------------------------
// Per-span attention pooling
__global__ void k_attn(const float* __restrict__ stok, const unsigned short* __restrict__ vtok,
                       const int* __restrict__ span_ids, const int* __restrict__ masks,
                       unsigned short* __restrict__ ctx) {
    int r = blockIdx.x, b = r / S_;
    unsigned short* out = ctx + (size_t)r * H_;
    int tid = threadIdx.x;
    __shared__ float w[NH_][L_];
    __shared__ int idxs[L_];
    __shared__ int s_len;
    if (tid == 0) {
        int m = masks[r];
        int st = span_ids[2 * r], en = span_ids[2 * r + 1];
        int len = m ? (en - st) : 0;
        len = len < 0 ? 0 : (len > L_ ? L_ : len);
        s_len = len;
    }
    __syncthreads();
    int len = s_len;
    if (len == 0) {
        for (int h2 = tid; h2 < H_ / 2; h2 += 256) ((unsigned*)out)[h2] = 0u;
        return;
    }
    if (tid < L_) {
        int p = span_ids[2 * r] + tid;
        idxs[tid] = p < 0 ? 0 : (p > T_ - 1 ? T_ - 1 : p);
    }
    __syncthreads();
    for (int i = tid; i < NH_ * L_; i += 256) {
        int n = i / L_, l = i % L_;
        w[n][l] = (l < len) ? stok[(size_t)(b * T_ + idxs[l]) * NH_ + n] * 0.125f : -INFINITY;
    }
    __syncthreads();
    if (tid < NH_) {
        float mx = -INFINITY;
        for (int l = 0; l < len; ++l) mx = fmaxf(mx, w[tid][l]);
        float sum = 0.f;
        for (int l = 0; l < len; ++l) { float e = __expf(w[tid][l] - mx); w[tid][l] = e; sum += e; }
        float inv = 1.f / sum;
        for (int l = 0; l < len; ++l) w[tid][l] *= inv;
    }
    __syncthreads();
    if (tid < 192) {
        int h0 = tid * 4, n = h0 >> 6;
        float a0 = 0.f, a1 = 0.f, a2 = 0.f, a3 = 0.f;
        for (int l = 0; l < len; ++l) {
            float wl = w[n][l];
            const unsigned short* vr = vtok + (size_t)(b * T_ + idxs[l]) * H_ + h0;
            uint2 u = *(const uint2*)vr;
            a0 += wl * bf2f((unsigned short)(u.x & 0xffff));
            a1 += wl * bf2f((unsigned short)(u.x >> 16));
            a2 += wl * bf2f((unsigned short)(u.y & 0xffff));
            a3 += wl * bf2f((unsigned short)(u.y >> 16));
        }
        uint2 o;
        o.x = (unsigned)f2bf(a0) | ((unsigned)f2bf(a1) << 16);
        o.y = (unsigned)f2bf(a2) | ((unsigned)f2bf(a3) << 16);
        *(uint2*)(out + h0) = o;
    }
}

// ---------------------------------------------------------------------------
// LayerNorm: out = LN(inp + res)*g + b, optional mask-zero, optional bf16 copy.
__global__ void k_ln(const float* __restrict__ inp, const float* __restrict__ res,
                     const float* __restrict__ g, const float* __restrict__ bt,
                     float* __restrict__ outp, unsigned short* __restrict__ outbf,
                     const int* __restrict__ masks, int res_broadcast, int apply_mask) {
    int r = blockIdx.x;
    const float* irow = inp + (size_t)r * H_;
    const float* rrow = res_broadcast ? res : res + (size_t)r * H_;
    float* orow = outp + (size_t)r * H_;
    int tid = threadIdx.x;
    float v[3];
    float lsum = 0.f;
#pragma unroll
    for (int i = 0; i < 3; ++i) {
        int h = tid + 256 * i;
        v[i] = irow[h] + rrow[h];
        lsum += v[i];
    }
    __shared__ float sh[256];
    sh[tid] = lsum;
    __syncthreads();
    for (int st = 128; st > 0; st >>= 1) {
        if (tid < st) sh[tid] += sh[tid + st];
        __syncthreads();
    }
    float mean = sh[0] * (1.f / H_);
    __syncthreads();
    float lvar = 0.f;
#pragma unroll
    for (int i = 0; i < 3; ++i) { float d = v[i] - mean; lvar += d * d; }
    sh[tid] = lvar;
    __syncthreads();
    for (int st = 128; st > 0; st >>= 1) {
        if (tid < st) sh[tid] += sh[tid + st];
        __syncthreads();
    }
    float var = sh[0] * (1.f / H_);
    float scale = rsqrtf(var + 1e-5f);
    float mfac = apply_mask ? (masks[r] ? 1.f : 0.f) : 1.f;
#pragma unroll
    for (int i = 0; i < 3; ++i) {
        int h = tid + 256 * i;
        float o = ((v[i] - mean) * scale * g[h] + bt[h]) * mfac;
        orow[h] = o;
        if (outbf) outbf[(size_t)r * H_ + h] = f2bf(o);
    }
}

// ---------------------------------------------------------------------------
extern "C" void kernel_launch(void* const* d_in, const int* in_sizes, int n_in,
                              void* d_out, int out_size, void* d_ws, size_t ws_size,
                              hipStream_t stream) {
    const float* token_reps = (const float*)d_in[0];
    const int*   span_ids   = (const int*)d_in[1];
    const int*   masks_raw  = (const int*)d_in[2];
    const float* pe   = (const float*)d_in[4];
    const float* dq   = (const float*)d_in[5];
    const float* in_w = (const float*)d_in[6];
    const float* in_b = (const float*)d_in[7];
    const float* ow   = (const float*)d_in[8];
    const float* ob   = (const float*)d_in[9];
    const float* g    = (const float*)d_in[10];
    const float* bt   = (const float*)d_in[11];
    const float* w1   = (const float*)d_in[12];
    const float* b1   = (const float*)d_in[13];
    const float* w2   = (const float*)d_in[14];
    const float* b2   = (const float*)d_in[15];

    const int BS = B_ * S_;        // 4096
    const int BT = B_ * T_;        // 1024

    // Workspace layout
    float* fws   = (float*)d_ws;
    float* stok  = fws;                         // 12288
    float* qv    = stok + BT * NH_;             // 768
    float* wqeff = qv + H_;                     // 9216
    float* A1    = wqeff + NH_ * H_;            // 3145728 (reused as f2)
    float* x1f   = A1 + (size_t)BS * H_;        // 3145728
    unsigned short* us   = (unsigned short*)(x1f + (size_t)BS * H_);
    unsigned short* xbf  = us;                       // 786432
    unsigned short* vtok = xbf + (size_t)BT * H_;    // 786432
    unsigned short* ctx  = vtok + (size_t)BT * H_;   // 3145728
    unsigned short* x1bf = ctx + (size_t)BS * H_;    // 3145728
    unsigned short* f1   = x1bf + (size_t)BS * H_;   // 12582912
    unsigned short* wvb  = f1 + (size_t)BS * IM_;    // 589824
    unsigned short* owb  = wvb + H_ * H_;            // 589824
    unsigned short* w1b  = owb + H_ * H_;            // 2359296
    unsigned short* w2b  = w1b + IM_ * H_;           // 2359296
    int* maskn = (int*)(w2b + H_ * IM_);             // 4096
    float* f2 = A1;

    // 0. small prep
    k_mask<<<1, 1024, 0, stream>>>(masks_raw, maskn);
    k_q<<<(H_ + 255) / 256, 256, 0, stream>>>(dq, in_w, in_b, qv);
    k_wqeff<<<(NH_ * H_ + 255) / 256, 256, 0, stream>>>(qv, in_w, wqeff);
    // 1. weight casts (fused single launch)
    {
        long total8 = ((long)2 * H_ * H_ + (long)2 * IM_ * H_) / 8;
        k_castw<<<(int)(total8 / 256), 256, 0, stream>>>(
            in_w + (size_t)2 * H_ * H_, ow, w1, w2, wvb, owb, w1b, w2b);
    }
    // 2. x = bf16(token_reps + pe)
    k_addpe<<<(BT * H_ / 8 + 255) / 256, 256, 0, stream>>>(token_reps, pe, xbf);
    // 3. per-token per-head scores
    k_stok<<<BT, 256, 0, stream>>>(xbf, wqeff, stok);
    // 4. vtok = bf16(x @ Wv^T + bv)
    {
        dim3 grid(H_ / 128, BT / 128);
        gemm_bt<false, true><<<grid, 512, 0, stream>>>(xbf, wvb, in_b + 2 * H_, vtok, BT, H_, H_);
    }
    // 5. attention pooling -> ctx (bf16)
    k_attn<<<BS, 256, 0, stream>>>(stok, vtok, span_ids, maskn, ctx);
    // 6. A1 = ctx @ ow^T + ob (fp32)
    {
        dim3 grid(H_ / 128, BS / 128);
        gemm_bt<false, false><<<grid, 512, 0, stream>>>(ctx, owb, ob, A1, BS, H_, H_);
    }
    // 7. x1 = LN(A1 + dq) -> fp32 + bf16
    k_ln<<<BS, 256, 0, stream>>>(A1, dq, g, bt, x1f, x1bf, nullptr, 1, 0);
    // 8. f1 = bf16(relu(x1 @ w1^T + b1))
    {
        dim3 grid(IM_ / 128, BS / 128);
        gemm_bt<true, true><<<grid, 512, 0, stream>>>(x1bf, w1b, b1, f1, BS, IM_, H_);
    }
    // 9. f2 = f1 @ w2^T + b2 (fp32)
    {
        dim3 grid(H_ / 128, BS / 128);
        gemm_bt<false, false><<<grid, 512, 0, stream>>>(f1, w2b, b2, f2, BS, H_, IM_);
    }
    // 10. out = LN(f2 + x1) * mask
    k_ln<<<BS, 256, 0, stream>>>(f2, x1f, g, bt, (float*)d_out, nullptr, maskn, 0, 1);
}

// Round 4
// 306.526 us; speedup vs baseline: 4.9233x; 1.0077x over previous
//
#include <hip/hip_runtime.h>
#include <math.h>

// Problem constants
static constexpr int B_  = 2;
static constexpr int T_  = 512;
static constexpr int S_  = 2048;
static constexpr int H_  = 768;
static constexpr int L_  = 32;
static constexpr int NH_ = 12;
static constexpr int HD_ = 64;   // H/NH
static constexpr int IM_ = 3072; // 4*H

typedef __bf16 bf16x8 __attribute__((ext_vector_type(8)));
typedef float  f32x4  __attribute__((ext_vector_type(4)));

__device__ __forceinline__ float bf2f(unsigned short u) {
    return __uint_as_float(((unsigned)u) << 16);
}
__device__ __forceinline__ unsigned short f2bf(float f) {
    unsigned u = __float_as_uint(f);
    u += 0x7fffu + ((u >> 16) & 1u);   // RNE
    return (unsigned short)(u >> 16);
}
__device__ __forceinline__ void gl_lds16(const void* g, void* l) {
    __builtin_amdgcn_global_load_lds((const __attribute__((address_space(1))) void*)g,
                                     (__attribute__((address_space(3))) void*)l, 16, 0, 0);
}

// ---------------------------------------------------------------------------
// Mask normalization (int32 vs packed-byte autodetect)
__global__ void k_mask(const int* __restrict__ raw, int* __restrict__ mout) {
    __shared__ int bad;
    if (threadIdx.x == 0) bad = 0;
    __syncthreads();
    int v = raw[threadIdx.x];
    if (v != 0 && v != 1) bad = 1;
    __syncthreads();
    int byte_layout = bad;
    const unsigned char* rb = (const unsigned char*)raw;
    for (int i = threadIdx.x; i < B_ * S_; i += 1024)
        mout[i] = byte_layout ? (int)rb[i] : raw[i];
}

// q[i] = dq . Wq[i,:] + bq[i]
__global__ void k_q(const float* __restrict__ dq, const float* __restrict__ w,
                    const float* __restrict__ b, float* __restrict__ q) {
    int i = blockIdx.x * 256 + threadIdx.x;
    if (i >= H_) return;
    const float* row = w + (size_t)i * H_;
    float acc = b[i];
    for (int h = 0; h < H_; ++h) acc += dq[h] * row[h];
    q[i] = acc;
}

// Wq_eff[n,hh] = sum_d q[n*64+d] * Wk[n*64+d, hh]
__global__ void k_wqeff(const float* __restrict__ q, const float* __restrict__ w,
                        float* __restrict__ wq) {
    int i = blockIdx.x * 256 + threadIdx.x;
    if (i >= NH_ * H_) return;
    int n = i / H_, hh = i % H_;
    float acc = 0.f;
    for (int d = 0; d < HD_; ++d)
        acc += q[n * HD_ + d] * w[(size_t)(H_ + n * HD_ + d) * H_ + hh];
    wq[i] = acc;
}

// Fused weight cast: all four weight matrices fp32->bf16, 8 elems/thread.
__global__ void k_castw(const float* __restrict__ s0, const float* __restrict__ s1,
                        const float* __restrict__ s2, const float* __restrict__ s3,
                        unsigned short* __restrict__ d0, unsigned short* __restrict__ d1,
                        unsigned short* __restrict__ d2, unsigned short* __restrict__ d3) {
    const long n0 = (long)H_ * H_, n2 = (long)IM_ * H_;
    long gid = (long)(blockIdx.x * 256 + threadIdx.x) * 8;
    const float* s; unsigned short* d; long off;
    if (gid < n0)                { s = s0; d = d0; off = gid; }
    else if (gid < 2 * n0)       { s = s1; d = d1; off = gid - n0; }
    else if (gid < 2 * n0 + n2)  { s = s2; d = d2; off = gid - 2 * n0; }
    else                         { s = s3; d = d3; off = gid - 2 * n0 - n2; }
    float4 f0 = *(const float4*)(s + off);
    float4 f1 = *(const float4*)(s + off + 4);
    uint4 o;
    o.x = (unsigned)f2bf(f0.x) | ((unsigned)f2bf(f0.y) << 16);
    o.y = (unsigned)f2bf(f0.z) | ((unsigned)f2bf(f0.w) << 16);
    o.z = (unsigned)f2bf(f1.x) | ((unsigned)f2bf(f1.y) << 16);
    o.w = (unsigned)f2bf(f1.z) | ((unsigned)f2bf(f1.w) << 16);
    *(uint4*)(d + off) = o;
}

// x_bf = bf16(token_reps + pe), 8 elems/thread
__global__ void k_addpe(const float* __restrict__ tr, const float* __restrict__ pe,
                        unsigned short* __restrict__ x) {
    int i = (blockIdx.x * 256 + threadIdx.x) * 8;
    if (i >= B_ * T_ * H_) return;
    float4 a0 = *(const float4*)(tr + i);
    float4 a1 = *(const float4*)(tr + i + 4);
    const float* pp = pe + (i % (T_ * H_));
    float4 p0 = *(const float4*)pp;
    float4 p1 = *(const float4*)(pp + 4);
    uint4 o;
    o.x = (unsigned)f2bf(a0.x + p0.x) | ((unsigned)f2bf(a0.y + p0.y) << 16);
    o.y = (unsigned)f2bf(a0.z + p0.z) | ((unsigned)f2bf(a0.w + p0.w) << 16);
    o.z = (unsigned)f2bf(a1.x + p1.x) | ((unsigned)f2bf(a1.y + p1.y) << 16);
    o.w = (unsigned)f2bf(a1.z + p1.z) | ((unsigned)f2bf(a1.w + p1.w) << 16);
    *(uint4*)(x + i) = o;
}

// stok[bt,n] = x_bf[bt,:] . wqeff[n,:]
__global__ void k_stok(const unsigned short* __restrict__ x, const float* __restrict__ wq,
                       float* __restrict__ stok) {
    int bt = blockIdx.x;
    int lane = threadIdx.x & 63, w = threadIdx.x >> 6;
    const unsigned short* xr = x + (size_t)bt * H_;
    float xv[12];
#pragma unroll
    for (int k = 0; k < 12; ++k) xv[k] = bf2f(xr[lane + 64 * k]);
#pragma unroll
    for (int hh = 0; hh < 3; ++hh) {
        int n = w * 3 + hh;
        const float* wr = wq + (size_t)n * H_;
        float acc = 0.f;
#pragma unroll
        for (int k = 0; k < 12; ++k) acc += xv[k] * wr[lane + 64 * k];
        for (int m = 32; m; m >>= 1) acc += __shfl_xor(acc, m, 64);
        if (lane == 0) stok[bt * NH_ + n] = acc;
    }
}

// ---------------------------------------------------------------------------
// bf16 MFMA GEMM, 3-deep software pipeline with raw barriers + manual vmcnt.
// C[M,N] = A[M,K] @ W[N,K]^T + bias, opt ReLU. 128x128 tile, BK=32,
// 512 thr = 8 waves, each wave 32x64 = 2x4 MFMA 16x16x32.
// Per wave per tile: exactly 2 global_load_lds ops => vmcnt arithmetic below.
template <bool RELU, bool OBF>
__global__ __launch_bounds__(512)
void gemm_bt(const unsigned short* __restrict__ A, const unsigned short* __restrict__ W,
             const float* __restrict__ bias, void* __restrict__ Cout,
             int M, int N, int K) {
    constexpr int D = 3;                       // pipeline depth
    __shared__ unsigned short As[D * 128 * 32];
    __shared__ unsigned short Bs[D * 128 * 32];
    const int bm = blockIdx.y * 128, bn = blockIdx.x * 128;
    const int tid = threadIdx.x, lane = tid & 63, wid = tid >> 6;   // 0..7
    const int wm = (wid >> 1) * 32, wn = (wid & 1) * 64;
    // staging: wave w loads rows [16w,16w+16) of A-tile and of B-tile (1KB each)
    const int r4 = lane >> 2, kg = (lane & 3) * 8;
    const unsigned short* agp = A + (size_t)(bm + wid * 16 + r4) * K + kg;
    const unsigned short* bgp = W + (size_t)(bn + wid * 16 + r4) * K + kg;

    f32x4 acc[2][4];
#pragma unroll
    for (int i = 0; i < 2; ++i)
#pragma unroll
        for (int j = 0; j < 4; ++j) acc[i][j] = f32x4{0.f, 0.f, 0.f, 0.f};

    const int mrow = lane & 15, kq = (lane >> 4) * 8;
    const int NIT = K >> 5;
    // prologue: issue up to D tiles
    const int npre = NIT < D ? NIT : D;
    for (int p = 0; p < npre; ++p) {
        gl_lds16(agp + (p << 5), As + p * 4096 + wid * 512);
        gl_lds16(bgp + (p << 5), Bs + p * 4096 + wid * 512);
    }
    int buf = 0;
    for (int it = 0; it < NIT; ++it) {
        // wait for tile `it`'s 2 loads (this wave's oldest outstanding pair)
        int rem = NIT - it;
        if (rem > 2)       asm volatile("s_waitcnt vmcnt(4)" ::: "memory");
        else if (rem == 2) asm volatile("s_waitcnt vmcnt(2)" ::: "memory");
        else               asm volatile("s_waitcnt vmcnt(0)" ::: "memory");
        asm volatile("s_barrier" ::: "memory");   // tile `it` fully staged (all waves)
        const unsigned short* cA = As + buf * 4096;
        const unsigned short* cB = Bs + buf * 4096;
        bf16x8 af[2], bfr[4];
#pragma unroll
        for (int i = 0; i < 2; ++i)
            af[i] = *(const bf16x8*)(cA + (wm + i * 16 + mrow) * 32 + kq);
#pragma unroll
        for (int j = 0; j < 4; ++j)
            bfr[j] = *(const bf16x8*)(cB + (wn + j * 16 + mrow) * 32 + kq);
#pragma unroll
        for (int i = 0; i < 2; ++i)
#pragma unroll
            for (int j = 0; j < 4; ++j)
                acc[i][j] = __builtin_amdgcn_mfma_f32_16x16x32_bf16(af[i], bfr[j], acc[i][j], 0, 0, 0);
        asm volatile("s_barrier" ::: "memory");   // all waves done reading buf
        if (it + D < NIT) {                       // refill freed buffer
            int k0 = (it + D) << 5;
            gl_lds16(agp + k0, As + buf * 4096 + wid * 512);
            gl_lds16(bgp + k0, Bs + buf * 4096 + wid * 512);
        }
        buf = (buf + 1 == D) ? 0 : buf + 1;
    }

    // epilogue: C/D layout col=lane&15, row=(lane>>4)*4+reg (verified m89/m91)
    const int lr = (lane >> 4) * 4, lc = lane & 15;
#pragma unroll
    for (int j = 0; j < 4; ++j) {
        int col = bn + wn + j * 16 + lc;
        float bv = bias[col];
#pragma unroll
        for (int i = 0; i < 2; ++i) {
            int row0 = bm + wm + i * 16 + lr;
#pragma unroll
            for (int r = 0; r < 4; ++r) {
                float v = acc[i][j][r] + bv;
                if (RELU) v = fmaxf(v, 0.f);
                if (OBF)
                    ((unsigned short*)Cout)[(size_t)(row0 + r) * N + col] = f2bf(v);
                else
                    ((float*)Cout)[(size_t)(row0 + r) * N + col] = v;
            }
        }
    }
}

// ---------------------------------------------------------------------------
// Per-span attention pooling
__global__ void k_attn(const float* __restrict__ stok, const unsigned short* __restrict__ vtok,
                       const int* __restrict__ span_ids, const int* __restrict__ masks,
                       unsigned short* __restrict__ ctx) {
    int r = blockIdx.x, b = r / S_;
    unsigned short* out = ctx + (size_t)r * H_;
    int tid = threadIdx.x;
    __shared__ float w[NH_][L_];
    __shared__ int idxs[L_];
    __shared__ int s_len;
    if (tid == 0) {
        int m = masks[r];
        int st = span_ids[2 * r], en = span_ids[2 * r + 1];
        int len = m ? (en - st) : 0;
        len = len < 0 ? 0 : (len > L_ ? L_ : len);
        s_len = len;
    }
    __syncthreads();
    int len = s_len;
    if (len == 0) {
        for (int h2 = tid; h2 < H_ / 2; h2 += 256) ((unsigned*)out)[h2] = 0u;
        return;
    }
    if (tid < L_) {
        int p = span_ids[2 * r] + tid;
        idxs[tid] = p < 0 ? 0 : (p > T_ - 1 ? T_ - 1 : p);
    }
    __syncthreads();
    for (int i = tid; i < NH_ * L_; i += 256) {
        int n = i / L_, l = i % L_;
        w[n][l] = (l < len) ? stok[(size_t)(b * T_ + idxs[l]) * NH_ + n] * 0.125f : -INFINITY;
    }
    __syncthreads();
    if (tid < NH_) {
        float mx = -INFINITY;
        for (int l = 0; l < len; ++l) mx = fmaxf(mx, w[tid][l]);
        float sum = 0.f;
        for (int l = 0; l < len; ++l) { float e = __expf(w[tid][l] - mx); w[tid][l] = e; sum += e; }
        float inv = 1.f / sum;
        for (int l = 0; l < len; ++l) w[tid][l] *= inv;
    }
    __syncthreads();
    if (tid < 192) {
        int h0 = tid * 4, n = h0 >> 6;
        float a0 = 0.f, a1 = 0.f, a2 = 0.f, a3 = 0.f;
        for (int l = 0; l < len; ++l) {
            float wl = w[n][l];
            const unsigned short* vr = vtok + (size_t)(b * T_ + idxs[l]) * H_ + h0;
            uint2 u = *(const uint2*)vr;
            a0 += wl * bf2f((unsigned short)(u.x & 0xffff));
            a1 += wl * bf2f((unsigned short)(u.x >> 16));
            a2 += wl * bf2f((unsigned short)(u.y & 0xffff));
            a3 += wl * bf2f((unsigned short)(u.y >> 16));
        }
        uint2 o;
        o.x = (unsigned)f2bf(a0) | ((unsigned)f2bf(a1) << 16);
        o.y = (unsigned)f2bf(a2) | ((unsigned)f2bf(a3) << 16);
        *(uint2*)(out + h0) = o;
    }
}

// ---------------------------------------------------------------------------
// LayerNorm: out = LN(inp + res)*g + b, optional mask-zero, optional bf16 copy.
__global__ void k_ln(const float* __restrict__ inp, const float* __restrict__ res,
                     const float* __restrict__ g, const float* __restrict__ bt,
                     float* __restrict__ outp, unsigned short* __restrict__ outbf,
                     const int* __restrict__ masks, int res_broadcast, int apply_mask) {
    int r = blockIdx.x;
    const float* irow = inp + (size_t)r * H_;
    const float* rrow = res_broadcast ? res : res + (size_t)r * H_;
    float* orow = outp + (size_t)r * H_;
    int tid = threadIdx.x;
    float v[3];
    float lsum = 0.f;
#pragma unroll
    for (int i = 0; i < 3; ++i) {
        int h = tid + 256 * i;
        v[i] = irow[h] + rrow[h];
        lsum += v[i];
    }
    __shared__ float sh[256];
    sh[tid] = lsum;
    __syncthreads();
    for (int st = 128; st > 0; st >>= 1) {
        if (tid < st) sh[tid] += sh[tid + st];
        __syncthreads();
    }
    float mean = sh[0] * (1.f / H_);
    __syncthreads();
    float lvar = 0.f;
#pragma unroll
    for (int i = 0; i < 3; ++i) { float d = v[i] - mean; lvar += d * d; }
    sh[tid] = lvar;
    __syncthreads();
    for (int st = 128; st > 0; st >>= 1) {
        if (tid < st) sh[tid] += sh[tid + st];
        __syncthreads();
    }
    float var = sh[0] * (1.f / H_);
    float scale = rsqrtf(var + 1e-5f);
    float mfac = apply_mask ? (masks[r] ? 1.f : 0.f) : 1.f;
#pragma unroll
    for (int i = 0; i < 3; ++i) {
        int h = tid + 256 * i;
        float o = ((v[i] - mean) * scale * g[h] + bt[h]) * mfac;
        orow[h] = o;
        if (outbf) outbf[(size_t)r * H_ + h] = f2bf(o);
    }
}

// ---------------------------------------------------------------------------
extern "C" void kernel_launch(void* const* d_in, const int* in_sizes, int n_in,
                              void* d_out, int out_size, void* d_ws, size_t ws_size,
                              hipStream_t stream) {
    const float* token_reps = (const float*)d_in[0];
    const int*   span_ids   = (const int*)d_in[1];
    const int*   masks_raw  = (const int*)d_in[2];
    const float* pe   = (const float*)d_in[4];
    const float* dq   = (const float*)d_in[5];
    const float* in_w = (const float*)d_in[6];
    const float* in_b = (const float*)d_in[7];
    const float* ow   = (const float*)d_in[8];
    const float* ob   = (const float*)d_in[9];
    const float* g    = (const float*)d_in[10];
    const float* bt   = (const float*)d_in[11];
    const float* w1   = (const float*)d_in[12];
    const float* b1   = (const float*)d_in[13];
    const float* w2   = (const float*)d_in[14];
    const float* b2   = (const float*)d_in[15];

    const int BS = B_ * S_;        // 4096
    const int BT = B_ * T_;        // 1024

    // Workspace layout
    float* fws   = (float*)d_ws;
    float* stok  = fws;                         // 12288
    float* qv    = stok + BT * NH_;             // 768
    float* wqeff = qv + H_;                     // 9216
    float* A1    = wqeff + NH_ * H_;            // 3145728 (reused as f2)
    float* x1f   = A1 + (size_t)BS * H_;        // 3145728
    unsigned short* us   = (unsigned short*)(x1f + (size_t)BS * H_);
    unsigned short* xbf  = us;                       // 786432
    unsigned short* vtok = xbf + (size_t)BT * H_;    // 786432
    unsigned short* ctx  = vtok + (size_t)BT * H_;   // 3145728
    unsigned short* x1bf = ctx + (size_t)BS * H_;    // 3145728
    unsigned short* f1   = x1bf + (size_t)BS * H_;   // 12582912
    unsigned short* wvb  = f1 + (size_t)BS * IM_;    // 589824
    unsigned short* owb  = wvb + H_ * H_;            // 589824
    unsigned short* w1b  = owb + H_ * H_;            // 2359296
    unsigned short* w2b  = w1b + IM_ * H_;           // 2359296
    int* maskn = (int*)(w2b + H_ * IM_);             // 4096
    float* f2 = A1;

    // 0. small prep
    k_mask<<<1, 1024, 0, stream>>>(masks_raw, maskn);
    k_q<<<(H_ + 255) / 256, 256, 0, stream>>>(dq, in_w, in_b, qv);
    k_wqeff<<<(NH_ * H_ + 255) / 256, 256, 0, stream>>>(qv, in_w, wqeff);
    // 1. weight casts (fused single launch)
    {
        long total8 = ((long)2 * H_ * H_ + (long)2 * IM_ * H_) / 8;
        k_castw<<<(int)(total8 / 256), 256, 0, stream>>>(
            in_w + (size_t)2 * H_ * H_, ow, w1, w2, wvb, owb, w1b, w2b);
    }
    // 2. x = bf16(token_reps + pe)
    k_addpe<<<(BT * H_ / 8 + 255) / 256, 256, 0, stream>>>(token_reps, pe, xbf);
    // 3. per-token per-head scores
    k_stok<<<BT, 256, 0, stream>>>(xbf, wqeff, stok);
    // 4. vtok = bf16(x @ Wv^T + bv)
    {
        dim3 grid(H_ / 128, BT / 128);
        gemm_bt<false, true><<<grid, 512, 0, stream>>>(xbf, wvb, in_b + 2 * H_, vtok, BT, H_, H_);
    }
    // 5. attention pooling -> ctx (bf16)
    k_attn<<<BS, 256, 0, stream>>>(stok, vtok, span_ids, maskn, ctx);
    // 6. A1 = ctx @ ow^T + ob (fp32)
    {
        dim3 grid(H_ / 128, BS / 128);
        gemm_bt<false, false><<<grid, 512, 0, stream>>>(ctx, owb, ob, A1, BS, H_, H_);
    }
    // 7. x1 = LN(A1 + dq) -> fp32 + bf16
    k_ln<<<BS, 256, 0, stream>>>(A1, dq, g, bt, x1f, x1bf, nullptr, 1, 0);
    // 8. f1 = bf16(relu(x1 @ w1^T + b1))
    {
        dim3 grid(IM_ / 128, BS / 128);
        gemm_bt<true, true><<<grid, 512, 0, stream>>>(x1bf, w1b, b1, f1, BS, IM_, H_);
    }
    // 9. f2 = f1 @ w2^T + b2 (fp32)
    {
        dim3 grid(H_ / 128, BS / 128);
        gemm_bt<false, false><<<grid, 512, 0, stream>>>(f1, w2b, b2, f2, BS, H_, IM_);
    }
    // 10. out = LN(f2 + x1) * mask
    k_ln<<<BS, 256, 0, stream>>>(f2, x1f, g, bt, (float*)d_out, nullptr, maskn, 0, 1);
}

// Round 5
// 296.375 us; speedup vs baseline: 5.0919x; 1.0342x over previous
//
#include <hip/hip_runtime.h>
#include <math.h>

// Problem constants
static constexpr int B_  = 2;
static constexpr int T_  = 512;
static constexpr int S_  = 2048;
static constexpr int H_  = 768;
static constexpr int L_  = 32;
static constexpr int NH_ = 12;
static constexpr int HD_ = 64;   // H/NH
static constexpr int IM_ = 3072; // 4*H

typedef __bf16 bf16x8 __attribute__((ext_vector_type(8)));
typedef float  f32x4  __attribute__((ext_vector_type(4)));

__device__ __forceinline__ float bf2f(unsigned short u) {
    return __uint_as_float(((unsigned)u) << 16);
}
__device__ __forceinline__ unsigned short f2bf(float f) {
    unsigned u = __float_as_uint(f);
    u += 0x7fffu + ((u >> 16) & 1u);   // RNE
    return (unsigned short)(u >> 16);
}
__device__ __forceinline__ void gl_lds16(const void* g, void* l) {
    __builtin_amdgcn_global_load_lds((const __attribute__((address_space(1))) void*)g,
                                     (__attribute__((address_space(3))) void*)l, 16, 0, 0);
}

// ---------------------------------------------------------------------------
// Mask normalization (int32 vs packed-byte autodetect)
__global__ void k_mask(const int* __restrict__ raw, int* __restrict__ mout) {
    __shared__ int bad;
    if (threadIdx.x == 0) bad = 0;
    __syncthreads();
    int v = raw[threadIdx.x];
    if (v != 0 && v != 1) bad = 1;
    __syncthreads();
    int byte_layout = bad;
    const unsigned char* rb = (const unsigned char*)raw;
    for (int i = threadIdx.x; i < B_ * S_; i += 1024)
        mout[i] = byte_layout ? (int)rb[i] : raw[i];
}

// q[i] = dq . Wq[i,:] + bq[i]  — one wave per output row (coalesced over h)
__global__ void k_q(const float* __restrict__ dq, const float* __restrict__ w,
                    const float* __restrict__ b, float* __restrict__ q) {
    int wv = threadIdx.x >> 6, lane = threadIdx.x & 63;
    int i = blockIdx.x * 4 + wv;             // 192 blocks x 4 waves = 768 rows
    const float* row = w + (size_t)i * H_;
    float acc = 0.f;
#pragma unroll
    for (int k = 0; k < 12; ++k) acc += dq[lane + 64 * k] * row[lane + 64 * k];
    for (int m = 32; m; m >>= 1) acc += __shfl_xor(acc, m, 64);
    if (lane == 0) q[i] = acc + b[i];
}

// Wq_eff[n,hh] = sum_d q[n*64+d] * Wk[n*64+d, hh]
__global__ void k_wqeff(const float* __restrict__ q, const float* __restrict__ w,
                        float* __restrict__ wq) {
    int i = blockIdx.x * 256 + threadIdx.x;
    if (i >= NH_ * H_) return;
    int n = i / H_, hh = i % H_;
    float acc = 0.f;
    for (int d = 0; d < HD_; ++d)
        acc += q[n * HD_ + d] * w[(size_t)(H_ + n * HD_ + d) * H_ + hh];
    wq[i] = acc;
}

// Fused weight cast: all four weight matrices fp32->bf16, 8 elems/thread.
__global__ void k_castw(const float* __restrict__ s0, const float* __restrict__ s1,
                        const float* __restrict__ s2, const float* __restrict__ s3,
                        unsigned short* __restrict__ d0, unsigned short* __restrict__ d1,
                        unsigned short* __restrict__ d2, unsigned short* __restrict__ d3) {
    const long n0 = (long)H_ * H_, n2 = (long)IM_ * H_;
    long gid = (long)(blockIdx.x * 256 + threadIdx.x) * 8;
    const float* s; unsigned short* d; long off;
    if (gid < n0)                { s = s0; d = d0; off = gid; }
    else if (gid < 2 * n0)       { s = s1; d = d1; off = gid - n0; }
    else if (gid < 2 * n0 + n2)  { s = s2; d = d2; off = gid - 2 * n0; }
    else                         { s = s3; d = d3; off = gid - 2 * n0 - n2; }
    float4 f0 = *(const float4*)(s + off);
    float4 f1 = *(const float4*)(s + off + 4);
    uint4 o;
    o.x = (unsigned)f2bf(f0.x) | ((unsigned)f2bf(f0.y) << 16);
    o.y = (unsigned)f2bf(f0.z) | ((unsigned)f2bf(f0.w) << 16);
    o.z = (unsigned)f2bf(f1.x) | ((unsigned)f2bf(f1.y) << 16);
    o.w = (unsigned)f2bf(f1.z) | ((unsigned)f2bf(f1.w) << 16);
    *(uint4*)(d + off) = o;
}

// x_bf = bf16(token_reps + pe), 8 elems/thread
__global__ void k_addpe(const float* __restrict__ tr, const float* __restrict__ pe,
                        unsigned short* __restrict__ x) {
    int i = (blockIdx.x * 256 + threadIdx.x) * 8;
    if (i >= B_ * T_ * H_) return;
    float4 a0 = *(const float4*)(tr + i);
    float4 a1 = *(const float4*)(tr + i + 4);
    const float* pp = pe + (i % (T_ * H_));
    float4 p0 = *(const float4*)pp;
    float4 p1 = *(const float4*)(pp + 4);
    uint4 o;
    o.x = (unsigned)f2bf(a0.x + p0.x) | ((unsigned)f2bf(a0.y + p0.y) << 16);
    o.y = (unsigned)f2bf(a0.z + p0.z) | ((unsigned)f2bf(a0.w + p0.w) << 16);
    o.z = (unsigned)f2bf(a1.x + p1.x) | ((unsigned)f2bf(a1.y + p1.y) << 16);
    o.w = (unsigned)f2bf(a1.z + p1.z) | ((unsigned)f2bf(a1.w + p1.w) << 16);
    *(uint4*)(x + i) = o;
}

// stok[bt,n] = x_bf[bt,:] . wqeff[n,:]
__global__ void k_stok(const unsigned short* __restrict__ x, const float* __restrict__ wq,
                       float* __restrict__ stok) {
    int bt = blockIdx.x;
    int lane = threadIdx.x & 63, w = threadIdx.x >> 6;
    const unsigned short* xr = x + (size_t)bt * H_;
    float xv[12];
#pragma unroll
    for (int k = 0; k < 12; ++k) xv[k] = bf2f(xr[lane + 64 * k]);
#pragma unroll
    for (int hh = 0; hh < 3; ++hh) {
        int n = w * 3 + hh;
        const float* wr = wq + (size_t)n * H_;
        float acc = 0.f;
#pragma unroll
        for (int k = 0; k < 12; ++k) acc += xv[k] * wr[lane + 64 * k];
        for (int m = 32; m; m >>= 1) acc += __shfl_xor(acc, m, 64);
        if (lane == 0) stok[bt * NH_ + n] = acc;
    }
}

// ---------------------------------------------------------------------------
// bf16 MFMA GEMM, 6-deep software pipeline with raw barriers + manual vmcnt.
// C[M,N] = A[M,K] @ W[N,K]^T + bias, opt ReLU. 128x128 tile, BK=32,
// 512 thr = 8 waves, each wave 32x64 = 2x4 MFMA 16x16x32.
// Per wave per tile: exactly 2 global_load_lds ops. D=6 => up to 12 loads
// (96 KB/CU) in flight: Little's-law headroom over HBM latency (~900cyc).
// All GEMM grids here are <= 768 blocks => ~1 block/CU, so 96 KB LDS is free.
template <bool RELU, bool OBF>
__global__ __launch_bounds__(512)
void gemm_bt(const unsigned short* __restrict__ A, const unsigned short* __restrict__ W,
             const float* __restrict__ bias, void* __restrict__ Cout,
             int M, int N, int K) {
    constexpr int D = 6;                       // pipeline depth
    __shared__ unsigned short As[D * 128 * 32];
    __shared__ unsigned short Bs[D * 128 * 32];
    const int bm = blockIdx.y * 128, bn = blockIdx.x * 128;
    const int tid = threadIdx.x, lane = tid & 63, wid = tid >> 6;   // 0..7
    const int wm = (wid >> 1) * 32, wn = (wid & 1) * 64;
    // staging: wave w loads rows [16w,16w+16) of A-tile and of B-tile (1KB each)
    const int r4 = lane >> 2, kg = (lane & 3) * 8;
    const unsigned short* agp = A + (size_t)(bm + wid * 16 + r4) * K + kg;
    const unsigned short* bgp = W + (size_t)(bn + wid * 16 + r4) * K + kg;

    f32x4 acc[2][4];
#pragma unroll
    for (int i = 0; i < 2; ++i)
#pragma unroll
        for (int j = 0; j < 4; ++j) acc[i][j] = f32x4{0.f, 0.f, 0.f, 0.f};

    const int mrow = lane & 15, kq = (lane >> 4) * 8;
    const int NIT = K >> 5;
    // prologue: issue up to D tiles
    const int npre = NIT < D ? NIT : D;
    for (int p = 0; p < npre; ++p) {
        gl_lds16(agp + (p << 5), As + p * 4096 + wid * 512);
        gl_lds16(bgp + (p << 5), Bs + p * 4096 + wid * 512);
    }
    int buf = 0;
    for (int it = 0; it < NIT; ++it) {
        // wait until only loads for tiles after `it` remain: vmcnt(2*(min(rem,D)-1))
        int rem = NIT - it;
        if (rem >= 6)      asm volatile("s_waitcnt vmcnt(10)" ::: "memory");
        else if (rem == 5) asm volatile("s_waitcnt vmcnt(8)" ::: "memory");
        else if (rem == 4) asm volatile("s_waitcnt vmcnt(6)" ::: "memory");
        else if (rem == 3) asm volatile("s_waitcnt vmcnt(4)" ::: "memory");
        else if (rem == 2) asm volatile("s_waitcnt vmcnt(2)" ::: "memory");
        else               asm volatile("s_waitcnt vmcnt(0)" ::: "memory");
        asm volatile("s_barrier" ::: "memory");   // tile `it` fully staged (all waves)
        const unsigned short* cA = As + buf * 4096;
        const unsigned short* cB = Bs + buf * 4096;
        bf16x8 af[2], bfr[4];
#pragma unroll
        for (int i = 0; i < 2; ++i)
            af[i] = *(const bf16x8*)(cA + (wm + i * 16 + mrow) * 32 + kq);
#pragma unroll
        for (int j = 0; j < 4; ++j)
            bfr[j] = *(const bf16x8*)(cB + (wn + j * 16 + mrow) * 32 + kq);
#pragma unroll
        for (int i = 0; i < 2; ++i)
#pragma unroll
            for (int j = 0; j < 4; ++j)
                acc[i][j] = __builtin_amdgcn_mfma_f32_16x16x32_bf16(af[i], bfr[j], acc[i][j], 0, 0, 0);
        asm volatile("s_barrier" ::: "memory");   // all waves done reading buf
        if (it + D < NIT) {                       // refill freed buffer
            int k0 = (it + D) << 5;
            gl_lds16(agp + k0, As + buf * 4096 + wid * 512);
            gl_lds16(bgp + k0, Bs + buf * 4096 + wid * 512);
        }
        buf = (buf + 1 == D) ? 0 : buf + 1;
    }

    // epilogue: C/D layout col=lane&15, row=(lane>>4)*4+reg (verified m89/m91)
    const int lr = (lane >> 4) * 4, lc = lane & 15;
#pragma unroll
    for (int j = 0; j < 4; ++j) {
        int col = bn + wn + j * 16 + lc;
        float bv = bias[col];
#pragma unroll
        for (int i = 0; i < 2; ++i) {
            int row0 = bm + wm + i * 16 + lr;
#pragma unroll
            for (int r = 0; r < 4; ++r) {
                float v = acc[i][j][r] + bv;
                if (RELU) v = fmaxf(v, 0.f);
                if (OBF)
                    ((unsigned short*)Cout)[(size_t)(row0 + r) * N + col] = f2bf(v);
                else
                    ((float*)Cout)[(size_t)(row0 + r) * N + col] = v;
            }
        }
    }
}

// ---------------------------------------------------------------------------
// Per-span attention pooling
__global__ void k_attn(const float* __restrict__ stok, const unsigned short* __restrict__ vtok,
                       const int* __restrict__ span_ids, const int* __restrict__ masks,
                       unsigned short* __restrict__ ctx) {
    int r = blockIdx.x, b = r / S_;
    unsigned short* out = ctx + (size_t)r * H_;
    int tid = threadIdx.x;
    __shared__ float w[NH_][L_];
    __shared__ int idxs[L_];
    __shared__ int s_len;
    if (tid == 0) {
        int m = masks[r];
        int st = span_ids[2 * r], en = span_ids[2 * r + 1];
        int len = m ? (en - st) : 0;
        len = len < 0 ? 0 : (len > L_ ? L_ : len);
        s_len = len;
    }
    __syncthreads();
    int len = s_len;
    if (len == 0) {
        for (int h2 = tid; h2 < H_ / 2; h2 += 256) ((unsigned*)out)[h2] = 0u;
        return;
    }
    if (tid < L_) {
        int p = span_ids[2 * r] + tid;
        idxs[tid] = p < 0 ? 0 : (p > T_ - 1 ? T_ - 1 : p);
    }
    __syncthreads();
    for (int i = tid; i < NH_ * L_; i += 256) {
        int n = i / L_, l = i % L_;
        w[n][l] = (l < len) ? stok[(size_t)(b * T_ + idxs[l]) * NH_ + n] * 0.125f : -INFINITY;
    }
    __syncthreads();
    if (tid < NH_) {
        float mx = -INFINITY;
        for (int l = 0; l < len; ++l) mx = fmaxf(mx, w[tid][l]);
        float sum = 0.f;
        for (int l = 0; l < len; ++l) { float e = __expf(w[tid][l] - mx); w[tid][l] = e; sum += e; }
        float inv = 1.f / sum;
        for (int l = 0; l < len; ++l) w[tid][l] *= inv;
    }
    __syncthreads();
    if (tid < 192) {
        int h0 = tid * 4, n = h0 >> 6;
        float a0 = 0.f, a1 = 0.f, a2 = 0.f, a3 = 0.f;
        for (int l = 0; l < len; ++l) {
            float wl = w[n][l];
            const unsigned short* vr = vtok + (size_t)(b * T_ + idxs[l]) * H_ + h0;
            uint2 u = *(const uint2*)vr;
            a0 += wl * bf2f((unsigned short)(u.x & 0xffff));
            a1 += wl * bf2f((unsigned short)(u.x >> 16));
            a2 += wl * bf2f((unsigned short)(u.y & 0xffff));
            a3 += wl * bf2f((unsigned short)(u.y >> 16));
        }
        uint2 o;
        o.x = (unsigned)f2bf(a0) | ((unsigned)f2bf(a1) << 16);
        o.y = (unsigned)f2bf(a2) | ((unsigned)f2bf(a3) << 16);
        *(uint2*)(out + h0) = o;
    }
}

// ---------------------------------------------------------------------------
// LayerNorm: out = LN(inp + res)*g + b, optional mask-zero, optional bf16 copy.
__global__ void k_ln(const float* __restrict__ inp, const float* __restrict__ res,
                     const float* __restrict__ g, const float* __restrict__ bt,
                     float* __restrict__ outp, unsigned short* __restrict__ outbf,
                     const int* __restrict__ masks, int res_broadcast, int apply_mask) {
    int r = blockIdx.x;
    const float* irow = inp + (size_t)r * H_;
    const float* rrow = res_broadcast ? res : res + (size_t)r * H_;
    float* orow = outp + (size_t)r * H_;
    int tid = threadIdx.x;
    float v[3];
    float lsum = 0.f;
#pragma unroll
    for (int i = 0; i < 3; ++i) {
        int h = tid + 256 * i;
        v[i] = irow[h] + rrow[h];
        lsum += v[i];
    }
    __shared__ float sh[256];
    sh[tid] = lsum;
    __syncthreads();
    for (int st = 128; st > 0; st >>= 1) {
        if (tid < st) sh[tid] += sh[tid + st];
        __syncthreads();
    }
    float mean = sh[0] * (1.f / H_);
    __syncthreads();
    float lvar = 0.f;
#pragma unroll
    for (int i = 0; i < 3; ++i) { float d = v[i] - mean; lvar += d * d; }
    sh[tid] = lvar;
    __syncthreads();
    for (int st = 128; st > 0; st >>= 1) {
        if (tid < st) sh[tid] += sh[tid + st];
        __syncthreads();
    }
    float var = sh[0] * (1.f / H_);
    float scale = rsqrtf(var + 1e-5f);
    float mfac = apply_mask ? (masks[r] ? 1.f : 0.f) : 1.f;
#pragma unroll
    for (int i = 0; i < 3; ++i) {
        int h = tid + 256 * i;
        float o = ((v[i] - mean) * scale * g[h] + bt[h]) * mfac;
        orow[h] = o;
        if (outbf) outbf[(size_t)r * H_ + h] = f2bf(o);
    }
}

// ---------------------------------------------------------------------------
extern "C" void kernel_launch(void* const* d_in, const int* in_sizes, int n_in,
                              void* d_out, int out_size, void* d_ws, size_t ws_size,
                              hipStream_t stream) {
    const float* token_reps = (const float*)d_in[0];
    const int*   span_ids   = (const int*)d_in[1];
    const int*   masks_raw  = (const int*)d_in[2];
    const float* pe   = (const float*)d_in[4];
    const float* dq   = (const float*)d_in[5];
    const float* in_w = (const float*)d_in[6];
    const float* in_b = (const float*)d_in[7];
    const float* ow   = (const float*)d_in[8];
    const float* ob   = (const float*)d_in[9];
    const float* g    = (const float*)d_in[10];
    const float* bt   = (const float*)d_in[11];
    const float* w1   = (const float*)d_in[12];
    const float* b1   = (const float*)d_in[13];
    const float* w2   = (const float*)d_in[14];
    const float* b2   = (const float*)d_in[15];

    const int BS = B_ * S_;        // 4096
    const int BT = B_ * T_;        // 1024

    // Workspace layout
    float* fws   = (float*)d_ws;
    float* stok  = fws;                         // 12288
    float* qv    = stok + BT * NH_;             // 768
    float* wqeff = qv + H_;                     // 9216
    float* A1    = wqeff + NH_ * H_;            // 3145728 (reused as f2)
    float* x1f   = A1 + (size_t)BS * H_;        // 3145728
    unsigned short* us   = (unsigned short*)(x1f + (size_t)BS * H_);
    unsigned short* xbf  = us;                       // 786432
    unsigned short* vtok = xbf + (size_t)BT * H_;    // 786432
    unsigned short* ctx  = vtok + (size_t)BT * H_;   // 3145728
    unsigned short* x1bf = ctx + (size_t)BS * H_;    // 3145728
    unsigned short* f1   = x1bf + (size_t)BS * H_;   // 12582912
    unsigned short* wvb  = f1 + (size_t)BS * IM_;    // 589824
    unsigned short* owb  = wvb + H_ * H_;            // 589824
    unsigned short* w1b  = owb + H_ * H_;            // 2359296
    unsigned short* w2b  = w1b + IM_ * H_;           // 2359296
    int* maskn = (int*)(w2b + H_ * IM_);             // 4096
    float* f2 = A1;

    // 0. small prep
    k_mask<<<1, 1024, 0, stream>>>(masks_raw, maskn);
    k_q<<<H_ / 4, 256, 0, stream>>>(dq, in_w, in_b, qv);
    k_wqeff<<<(NH_ * H_ + 255) / 256, 256, 0, stream>>>(qv, in_w, wqeff);
    // 1. weight casts (fused single launch)
    {
        long total8 = ((long)2 * H_ * H_ + (long)2 * IM_ * H_) / 8;
        k_castw<<<(int)(total8 / 256), 256, 0, stream>>>(
            in_w + (size_t)2 * H_ * H_, ow, w1, w2, wvb, owb, w1b, w2b);
    }
    // 2. x = bf16(token_reps + pe)
    k_addpe<<<(BT * H_ / 8 + 255) / 256, 256, 0, stream>>>(token_reps, pe, xbf);
    // 3. per-token per-head scores
    k_stok<<<BT, 256, 0, stream>>>(xbf, wqeff, stok);
    // 4. vtok = bf16(x @ Wv^T + bv)
    {
        dim3 grid(H_ / 128, BT / 128);
        gemm_bt<false, true><<<grid, 512, 0, stream>>>(xbf, wvb, in_b + 2 * H_, vtok, BT, H_, H_);
    }
    // 5. attention pooling -> ctx (bf16)
    k_attn<<<BS, 256, 0, stream>>>(stok, vtok, span_ids, maskn, ctx);
    // 6. A1 = ctx @ ow^T + ob (fp32)
    {
        dim3 grid(H_ / 128, BS / 128);
        gemm_bt<false, false><<<grid, 512, 0, stream>>>(ctx, owb, ob, A1, BS, H_, H_);
    }
    // 7. x1 = LN(A1 + dq) -> fp32 + bf16
    k_ln<<<BS, 256, 0, stream>>>(A1, dq, g, bt, x1f, x1bf, nullptr, 1, 0);
    // 8. f1 = bf16(relu(x1 @ w1^T + b1))
    {
        dim3 grid(IM_ / 128, BS / 128);
        gemm_bt<true, true><<<grid, 512, 0, stream>>>(x1bf, w1b, b1, f1, BS, IM_, H_);
    }
    // 9. f2 = f1 @ w2^T + b2 (fp32)
    {
        dim3 grid(H_ / 128, BS / 128);
        gemm_bt<false, false><<<grid, 512, 0, stream>>>(f1, w2b, b2, f2, BS, H_, IM_);
    }
    // 10. out = LN(f2 + x1) * mask
    k_ln<<<BS, 256, 0, stream>>>(f2, x1f, g, bt, (float*)d_out, nullptr, maskn, 0, 1);
}

// Round 6
// 271.130 us; speedup vs baseline: 5.5660x; 1.0931x over previous
//
#include <hip/hip_runtime.h>
#include <math.h>

// Problem constants
static constexpr int B_  = 2;
static constexpr int T_  = 512;
static constexpr int S_  = 2048;
static constexpr int H_  = 768;
static constexpr int L_  = 32;
static constexpr int NH_ = 12;
static constexpr int HD_ = 64;   // H/NH
static constexpr int IM_ = 3072; // 4*H

typedef __bf16 bf16x8 __attribute__((ext_vector_type(8)));
typedef float  f32x4  __attribute__((ext_vector_type(4)));

__device__ __forceinline__ float bf2f(unsigned short u) {
    return __uint_as_float(((unsigned)u) << 16);
}
__device__ __forceinline__ unsigned short f2bf(float f) {
    unsigned u = __float_as_uint(f);
    u += 0x7fffu + ((u >> 16) & 1u);   // RNE
    return (unsigned short)(u >> 16);
}
__device__ __forceinline__ void gl_lds16(const void* g, void* l) {
    __builtin_amdgcn_global_load_lds((const __attribute__((address_space(1))) void*)g,
                                     (__attribute__((address_space(3))) void*)l, 16, 0, 0);
}

// ---------------------------------------------------------------------------
// Mask normalization (int32 vs packed-byte autodetect)
__global__ void k_mask(const int* __restrict__ raw, int* __restrict__ mout) {
    __shared__ int bad;
    if (threadIdx.x == 0) bad = 0;
    __syncthreads();
    int v = raw[threadIdx.x];
    if (v != 0 && v != 1) bad = 1;
    __syncthreads();
    int byte_layout = bad;
    const unsigned char* rb = (const unsigned char*)raw;
    for (int i = threadIdx.x; i < B_ * S_; i += 1024)
        mout[i] = byte_layout ? (int)rb[i] : raw[i];
}

// q[i] = dq . Wq[i,:] + bq[i]  — one wave per output row (coalesced over h)
__global__ void k_q(const float* __restrict__ dq, const float* __restrict__ w,
                    const float* __restrict__ b, float* __restrict__ q) {
    int wv = threadIdx.x >> 6, lane = threadIdx.x & 63;
    int i = blockIdx.x * 4 + wv;
    const float* row = w + (size_t)i * H_;
    float acc = 0.f;
#pragma unroll
    for (int k = 0; k < 12; ++k) acc += dq[lane + 64 * k] * row[lane + 64 * k];
    for (int m = 32; m; m >>= 1) acc += __shfl_xor(acc, m, 64);
    if (lane == 0) q[i] = acc + b[i];
}

// Wq_eff[n,hh] = sum_d q[n*64+d] * Wk[n*64+d, hh]
__global__ void k_wqeff(const float* __restrict__ q, const float* __restrict__ w,
                        float* __restrict__ wq) {
    int i = blockIdx.x * 256 + threadIdx.x;
    if (i >= NH_ * H_) return;
    int n = i / H_, hh = i % H_;
    float acc = 0.f;
    for (int d = 0; d < HD_; ++d)
        acc += q[n * HD_ + d] * w[(size_t)(H_ + n * HD_ + d) * H_ + hh];
    wq[i] = acc;
}

// Fused weight cast: all four weight matrices fp32->bf16, 8 elems/thread.
__global__ void k_castw(const float* __restrict__ s0, const float* __restrict__ s1,
                        const float* __restrict__ s2, const float* __restrict__ s3,
                        unsigned short* __restrict__ d0, unsigned short* __restrict__ d1,
                        unsigned short* __restrict__ d2, unsigned short* __restrict__ d3) {
    const long n0 = (long)H_ * H_, n2 = (long)IM_ * H_;
    long gid = (long)(blockIdx.x * 256 + threadIdx.x) * 8;
    const float* s; unsigned short* d; long off;
    if (gid < n0)                { s = s0; d = d0; off = gid; }
    else if (gid < 2 * n0)       { s = s1; d = d1; off = gid - n0; }
    else if (gid < 2 * n0 + n2)  { s = s2; d = d2; off = gid - 2 * n0; }
    else                         { s = s3; d = d3; off = gid - 2 * n0 - n2; }
    float4 f0 = *(const float4*)(s + off);
    float4 f1 = *(const float4*)(s + off + 4);
    uint4 o;
    o.x = (unsigned)f2bf(f0.x) | ((unsigned)f2bf(f0.y) << 16);
    o.y = (unsigned)f2bf(f0.z) | ((unsigned)f2bf(f0.w) << 16);
    o.z = (unsigned)f2bf(f1.x) | ((unsigned)f2bf(f1.y) << 16);
    o.w = (unsigned)f2bf(f1.z) | ((unsigned)f2bf(f1.w) << 16);
    *(uint4*)(d + off) = o;
}

// x_bf = bf16(token_reps + pe), 8 elems/thread
__global__ void k_addpe(const float* __restrict__ tr, const float* __restrict__ pe,
                        unsigned short* __restrict__ x) {
    int i = (blockIdx.x * 256 + threadIdx.x) * 8;
    if (i >= B_ * T_ * H_) return;
    float4 a0 = *(const float4*)(tr + i);
    float4 a1 = *(const float4*)(tr + i + 4);
    const float* pp = pe + (i % (T_ * H_));
    float4 p0 = *(const float4*)pp;
    float4 p1 = *(const float4*)(pp + 4);
    uint4 o;
    o.x = (unsigned)f2bf(a0.x + p0.x) | ((unsigned)f2bf(a0.y + p0.y) << 16);
    o.y = (unsigned)f2bf(a0.z + p0.z) | ((unsigned)f2bf(a0.w + p0.w) << 16);
    o.z = (unsigned)f2bf(a1.x + p1.x) | ((unsigned)f2bf(a1.y + p1.y) << 16);
    o.w = (unsigned)f2bf(a1.z + p1.z) | ((unsigned)f2bf(a1.w + p1.w) << 16);
    *(uint4*)(x + i) = o;
}

// stok[bt,n] = x_bf[bt,:] . wqeff[n,:]
__global__ void k_stok(const unsigned short* __restrict__ x, const float* __restrict__ wq,
                       float* __restrict__ stok) {
    int bt = blockIdx.x;
    int lane = threadIdx.x & 63, w = threadIdx.x >> 6;
    const unsigned short* xr = x + (size_t)bt * H_;
    float xv[12];
#pragma unroll
    for (int k = 0; k < 12; ++k) xv[k] = bf2f(xr[lane + 64 * k]);
#pragma unroll
    for (int hh = 0; hh < 3; ++hh) {
        int n = w * 3 + hh;
        const float* wr = wq + (size_t)n * H_;
        float acc = 0.f;
#pragma unroll
        for (int k = 0; k < 12; ++k) acc += xv[k] * wr[lane + 64 * k];
        for (int m = 32; m; m >>= 1) acc += __shfl_xor(acc, m, 64);
        if (lane == 0) stok[bt * NH_ + n] = acc;
    }
}

// ---------------------------------------------------------------------------
// bf16 MFMA GEMM: C[M,N] = A[M,K] @ W[N,K]^T + bias, opt ReLU.
// 128x128 tile, BK=64, 256 thr = 4 waves, wave 64x64 = 4x4 MFMA 16x16x32.
// LDS double-buffer; XOR bank swizzle (chunk ^= row&7) so fragment ds_read_b128
// is 2-way-per-bank (free); per-wave 8 global_load_lds per tile with vmcnt(8)
// steady-state waits (tile it+2 issued after the consume barrier of it).
template <bool RELU, bool OBF>
__global__ __launch_bounds__(256)
void gemm_bt(const unsigned short* __restrict__ A, const unsigned short* __restrict__ W,
             const float* __restrict__ bias, void* __restrict__ Cout,
             int M, int N, int K) {
    // tile buffers: 128 rows x 64 cols bf16 = 8192 shorts per buffer
    __shared__ unsigned short As[2 * 8192];
    __shared__ unsigned short Bs[2 * 8192];
    const int bm = blockIdx.y * 128, bn = blockIdx.x * 128;
    const int tid = threadIdx.x, lane = tid & 63, wid = tid >> 6;   // 0..3
    const int wm = (wid >> 1) * 64, wn = (wid & 1) * 64;
    // staging: wave stages 32 rows of A-tile and 32 rows of B-tile.
    // lane -> (r8 = lane>>3 row-in-8-group, c = lane&7 16B-chunk), stores
    // global chunk (c ^ r8) at position c  => bank-swizzled layout.
    const int r8 = lane >> 3, c8 = lane & 7;
    const int swc = (c8 ^ r8) * 8;                     // element offset in row
    const unsigned short* agp = A + (size_t)(bm + wid * 32 + r8) * K + swc;
    const unsigned short* bgp = W + (size_t)(bn + wid * 32 + r8) * K + swc;
    unsigned short* lA = As + wid * 2048;              // wave-uniform bases
    unsigned short* lB = Bs + wid * 2048;

    f32x4 acc[4][4];
#pragma unroll
    for (int i = 0; i < 4; ++i)
#pragma unroll
        for (int j = 0; j < 4; ++j) acc[i][j] = f32x4{0.f, 0.f, 0.f, 0.f};

    const int mrow = lane & 15;
    const int l7 = lane & 7;               // == row&7 for all fragment rows
    const int cq0 = lane >> 4;             // chunk within 32-k window (0..3)
    const int NIT = K >> 6;

    // prologue: stage tiles 0 and 1 (8 calls each, per-tile contiguous)
#pragma unroll
    for (int p = 0; p < 2; ++p) {
        const int k0 = p << 6;
        const int lo = p * 8192;
#pragma unroll
        for (int j = 0; j < 4; ++j) {
            gl_lds16(agp + (size_t)(8 * j) * K + k0, lA + lo + j * 512);
            gl_lds16(bgp + (size_t)(8 * j) * K + k0, lB + lo + j * 512);
        }
    }

    for (int it = 0; it < NIT; ++it) {
        if (it < NIT - 1) asm volatile("s_waitcnt vmcnt(8)" ::: "memory");
        else              asm volatile("s_waitcnt vmcnt(0)" ::: "memory");
        asm volatile("s_barrier" ::: "memory");        // tile `it` staged
        const int lo = (it & 1) * 8192;
        const unsigned short* cA = As + lo;
        const unsigned short* cB = Bs + lo;
        bf16x8 af[2][4], bfr[2][4];
#pragma unroll
        for (int s = 0; s < 2; ++s) {
            const int cq = s * 4 + cq0;
            const int sw = (cq ^ l7) * 8;
#pragma unroll
            for (int i = 0; i < 4; ++i)
                af[s][i] = *(const bf16x8*)(cA + (wm + i * 16 + mrow) * 64 + sw);
#pragma unroll
            for (int j = 0; j < 4; ++j)
                bfr[s][j] = *(const bf16x8*)(cB + (wn + j * 16 + mrow) * 64 + sw);
        }
#pragma unroll
        for (int s = 0; s < 2; ++s)
#pragma unroll
            for (int i = 0; i < 4; ++i)
#pragma unroll
                for (int j = 0; j < 4; ++j)
                    acc[i][j] = __builtin_amdgcn_mfma_f32_16x16x32_bf16(af[s][i], bfr[s][j], acc[i][j], 0, 0, 0);
        asm volatile("s_barrier" ::: "memory");        // all waves done with buf
        if (it + 2 < NIT) {                            // refill freed buffer
            const int k0 = (it + 2) << 6;
#pragma unroll
            for (int j = 0; j < 4; ++j) {
                gl_lds16(agp + (size_t)(8 * j) * K + k0, lA + lo + j * 512);
                gl_lds16(bgp + (size_t)(8 * j) * K + k0, lB + lo + j * 512);
            }
        }
    }

    // epilogue: C/D layout col=lane&15, row=(lane>>4)*4+reg (verified m89/m91)
    const int lr = (lane >> 4) * 4, lc = lane & 15;
#pragma unroll
    for (int j = 0; j < 4; ++j) {
        int col = bn + wn + j * 16 + lc;
        float bv = bias[col];
#pragma unroll
        for (int i = 0; i < 4; ++i) {
            int row0 = bm + wm + i * 16 + lr;
#pragma unroll
            for (int r = 0; r < 4; ++r) {
                float v = acc[i][j][r] + bv;
                if (RELU) v = fmaxf(v, 0.f);
                if (OBF)
                    ((unsigned short*)Cout)[(size_t)(row0 + r) * N + col] = f2bf(v);
                else
                    ((float*)Cout)[(size_t)(row0 + r) * N + col] = v;
            }
        }
    }
}

// ---------------------------------------------------------------------------
// Per-span attention pooling
__global__ void k_attn(const float* __restrict__ stok, const unsigned short* __restrict__ vtok,
                       const int* __restrict__ span_ids, const int* __restrict__ masks,
                       unsigned short* __restrict__ ctx) {
    int r = blockIdx.x, b = r / S_;
    unsigned short* out = ctx + (size_t)r * H_;
    int tid = threadIdx.x;
    __shared__ float w[NH_][L_];
    __shared__ int idxs[L_];
    __shared__ int s_len;
    if (tid == 0) {
        int m = masks[r];
        int st = span_ids[2 * r], en = span_ids[2 * r + 1];
        int len = m ? (en - st) : 0;
        len = len < 0 ? 0 : (len > L_ ? L_ : len);
        s_len = len;
    }
    __syncthreads();
    int len = s_len;
    if (len == 0) {
        for (int h2 = tid; h2 < H_ / 2; h2 += 256) ((unsigned*)out)[h2] = 0u;
        return;
    }
    if (tid < L_) {
        int p = span_ids[2 * r] + tid;
        idxs[tid] = p < 0 ? 0 : (p > T_ - 1 ? T_ - 1 : p);
    }
    __syncthreads();
    for (int i = tid; i < NH_ * L_; i += 256) {
        int n = i / L_, l = i % L_;
        w[n][l] = (l < len) ? stok[(size_t)(b * T_ + idxs[l]) * NH_ + n] * 0.125f : -INFINITY;
    }
    __syncthreads();
    if (tid < NH_) {
        float mx = -INFINITY;
        for (int l = 0; l < len; ++l) mx = fmaxf(mx, w[tid][l]);
        float sum = 0.f;
        for (int l = 0; l < len; ++l) { float e = __expf(w[tid][l] - mx); w[tid][l] = e; sum += e; }
        float inv = 1.f / sum;
        for (int l = 0; l < len; ++l) w[tid][l] *= inv;
    }
    __syncthreads();
    if (tid < 192) {
        int h0 = tid * 4, n = h0 >> 6;
        float a0 = 0.f, a1 = 0.f, a2 = 0.f, a3 = 0.f;
        for (int l = 0; l < len; ++l) {
            float wl = w[n][l];
            const unsigned short* vr = vtok + (size_t)(b * T_ + idxs[l]) * H_ + h0;
            uint2 u = *(const uint2*)vr;
            a0 += wl * bf2f((unsigned short)(u.x & 0xffff));
            a1 += wl * bf2f((unsigned short)(u.x >> 16));
            a2 += wl * bf2f((unsigned short)(u.y & 0xffff));
            a3 += wl * bf2f((unsigned short)(u.y >> 16));
        }
        uint2 o;
        o.x = (unsigned)f2bf(a0) | ((unsigned)f2bf(a1) << 16);
        o.y = (unsigned)f2bf(a2) | ((unsigned)f2bf(a3) << 16);
        *(uint2*)(out + h0) = o;
    }
}

// ---------------------------------------------------------------------------
// LayerNorm: out = LN(inp + res)*g + b, optional mask-zero, optional bf16 copy.
__global__ void k_ln(const float* __restrict__ inp, const float* __restrict__ res,
                     const float* __restrict__ g, const float* __restrict__ bt,
                     float* __restrict__ outp, unsigned short* __restrict__ outbf,
                     const int* __restrict__ masks, int res_broadcast, int apply_mask) {
    int r = blockIdx.x;
    const float* irow = inp + (size_t)r * H_;
    const float* rrow = res_broadcast ? res : res + (size_t)r * H_;
    float* orow = outp + (size_t)r * H_;
    int tid = threadIdx.x;
    float v[3];
    float lsum = 0.f;
#pragma unroll
    for (int i = 0; i < 3; ++i) {
        int h = tid + 256 * i;
        v[i] = irow[h] + rrow[h];
        lsum += v[i];
    }
    __shared__ float sh[256];
    sh[tid] = lsum;
    __syncthreads();
    for (int st = 128; st > 0; st >>= 1) {
        if (tid < st) sh[tid] += sh[tid + st];
        __syncthreads();
    }
    float mean = sh[0] * (1.f / H_);
    __syncthreads();
    float lvar = 0.f;
#pragma unroll
    for (int i = 0; i < 3; ++i) { float d = v[i] - mean; lvar += d * d; }
    sh[tid] = lvar;
    __syncthreads();
    for (int st = 128; st > 0; st >>= 1) {
        if (tid < st) sh[tid] += sh[tid + st];
        __syncthreads();
    }
    float var = sh[0] * (1.f / H_);
    float scale = rsqrtf(var + 1e-5f);
    float mfac = apply_mask ? (masks[r] ? 1.f : 0.f) : 1.f;
#pragma unroll
    for (int i = 0; i < 3; ++i) {
        int h = tid + 256 * i;
        float o = ((v[i] - mean) * scale * g[h] + bt[h]) * mfac;
        orow[h] = o;
        if (outbf) outbf[(size_t)r * H_ + h] = f2bf(o);
    }
}

// ---------------------------------------------------------------------------
extern "C" void kernel_launch(void* const* d_in, const int* in_sizes, int n_in,
                              void* d_out, int out_size, void* d_ws, size_t ws_size,
                              hipStream_t stream) {
    const float* token_reps = (const float*)d_in[0];
    const int*   span_ids   = (const int*)d_in[1];
    const int*   masks_raw  = (const int*)d_in[2];
    const float* pe   = (const float*)d_in[4];
    const float* dq   = (const float*)d_in[5];
    const float* in_w = (const float*)d_in[6];
    const float* in_b = (const float*)d_in[7];
    const float* ow   = (const float*)d_in[8];
    const float* ob   = (const float*)d_in[9];
    const float* g    = (const float*)d_in[10];
    const float* bt   = (const float*)d_in[11];
    const float* w1   = (const float*)d_in[12];
    const float* b1   = (const float*)d_in[13];
    const float* w2   = (const float*)d_in[14];
    const float* b2   = (const float*)d_in[15];

    const int BS = B_ * S_;        // 4096
    const int BT = B_ * T_;        // 1024

    // Workspace layout
    float* fws   = (float*)d_ws;
    float* stok  = fws;                         // 12288
    float* qv    = stok + BT * NH_;             // 768
    float* wqeff = qv + H_;                     // 9216
    float* A1    = wqeff + NH_ * H_;            // 3145728 (reused as f2)
    float* x1f   = A1 + (size_t)BS * H_;        // 3145728
    unsigned short* us   = (unsigned short*)(x1f + (size_t)BS * H_);
    unsigned short* xbf  = us;                       // 786432
    unsigned short* vtok = xbf + (size_t)BT * H_;    // 786432
    unsigned short* ctx  = vtok + (size_t)BT * H_;   // 3145728
    unsigned short* x1bf = ctx + (size_t)BS * H_;    // 3145728
    unsigned short* f1   = x1bf + (size_t)BS * H_;   // 12582912
    unsigned short* wvb  = f1 + (size_t)BS * IM_;    // 589824
    unsigned short* owb  = wvb + H_ * H_;            // 589824
    unsigned short* w1b  = owb + H_ * H_;            // 2359296
    unsigned short* w2b  = w1b + IM_ * H_;           // 2359296
    int* maskn = (int*)(w2b + H_ * IM_);             // 4096
    float* f2 = A1;

    // 0. small prep
    k_mask<<<1, 1024, 0, stream>>>(masks_raw, maskn);
    k_q<<<H_ / 4, 256, 0, stream>>>(dq, in_w, in_b, qv);
    k_wqeff<<<(NH_ * H_ + 255) / 256, 256, 0, stream>>>(qv, in_w, wqeff);
    // 1. weight casts (fused single launch)
    {
        long total8 = ((long)2 * H_ * H_ + (long)2 * IM_ * H_) / 8;
        k_castw<<<(int)(total8 / 256), 256, 0, stream>>>(
            in_w + (size_t)2 * H_ * H_, ow, w1, w2, wvb, owb, w1b, w2b);
    }
    // 2. x = bf16(token_reps + pe)
    k_addpe<<<(BT * H_ / 8 + 255) / 256, 256, 0, stream>>>(token_reps, pe, xbf);
    // 3. per-token per-head scores
    k_stok<<<BT, 256, 0, stream>>>(xbf, wqeff, stok);
    // 4. vtok = bf16(x @ Wv^T + bv)
    {
        dim3 grid(H_ / 128, BT / 128);
        gemm_bt<false, true><<<grid, 256, 0, stream>>>(xbf, wvb, in_b + 2 * H_, vtok, BT, H_, H_);
    }
    // 5. attention pooling -> ctx (bf16)
    k_attn<<<BS, 256, 0, stream>>>(stok, vtok, span_ids, maskn, ctx);
    // 6. A1 = ctx @ ow^T + ob (fp32)
    {
        dim3 grid(H_ / 128, BS / 128);
        gemm_bt<false, false><<<grid, 256, 0, stream>>>(ctx, owb, ob, A1, BS, H_, H_);
    }
    // 7. x1 = LN(A1 + dq) -> fp32 + bf16
    k_ln<<<BS, 256, 0, stream>>>(A1, dq, g, bt, x1f, x1bf, nullptr, 1, 0);
    // 8. f1 = bf16(relu(x1 @ w1^T + b1))
    {
        dim3 grid(IM_ / 128, BS / 128);
        gemm_bt<true, true><<<grid, 256, 0, stream>>>(x1bf, w1b, b1, f1, BS, IM_, H_);
    }
    // 9. f2 = f1 @ w2^T + b2 (fp32)
    {
        dim3 grid(H_ / 128, BS / 128);
        gemm_bt<false, false><<<grid, 256, 0, stream>>>(f1, w2b, b2, f2, BS, H_, IM_);
    }
    // 10. out = LN(f2 + x1) * mask
    k_ln<<<BS, 256, 0, stream>>>(f2, x1f, g, bt, (float*)d_out, nullptr, maskn, 0, 1);
}